// Round 4
// baseline (401.448 us; speedup 1.0000x reference)
//
#include <hip/hip_runtime.h>
#include <hip/hip_bf16.h>
#include <math.h>

constexpr int B = 256, NN = 512, EE = 511;

// ---- workspace layout (fp32 element offsets) ----
constexpr size_t F_NF    = 0;                               // node_feat  B*N*64
constexpr size_t F_EF    = F_NF   + (size_t)B*NN*64;        // edge_feat  B*E*16
constexpr size_t F_WCK   = F_EF   + (size_t)B*EE*16;        // fused K weight 144x256
constexpr size_t F_BCK   = F_WCK  + 144*256;
constexpr size_t F_WCV   = F_BCK  + 256;                    // fused V weight 144x256
constexpr size_t F_BCV   = F_WCV  + 144*256;
constexpr size_t F_WQ2   = F_BCV  + 256;                    // fused Q weight 64x256
constexpr size_t F_BQ2   = F_WQ2  + 64*256;
constexpr size_t F_Q     = F_BQ2  + 256;                    // q  B*256
constexpr size_t F_AW    = F_Q    + (size_t)B*256;          // per (b,h) score weights 80
constexpr size_t F_C0    = F_AW   + (size_t)B*4*80;         // per (b,h) score const
constexpr size_t F_SC    = F_C0   + (size_t)B*4;            // scores/attn B*4*E
constexpr size_t F_US    = F_SC   + (size_t)B*4*EE;         // weighted sums B*4*80
constexpr size_t F_CEGO  = F_US   + (size_t)B*4*80;         // c_ego B*256
constexpr size_t F_CVEC  = F_CEGO + (size_t)B*256;          // cvec  B*256
constexpr size_t F_SC2   = F_CVEC + (size_t)B*256;          // edge scores B*E
constexpr size_t F_ALPHA = F_SC2  + (size_t)B*EE;           // B*5
constexpr size_t F_TKI   = F_ALPHA+ (size_t)B*5;            // B*5 (ints)

// ---- output layout (fp32 elements) ----
constexpr size_t O_HEGO  = 0;          // B*256
constexpr size_t O_SEL   = 65536;      // B*5*6*256
constexpr size_t O_TKI   = 2031616;    // B*5
constexpr size_t O_ALPHA = 2032896;    // B*5

// =============== weight fusion: Wck=WkvK@Wik, Wcv=WkvV@Wiv, Wq2=Wq@Wiq ===============
__global__ void k_fuse(const float* Wkv, const float* bkv, const float* Wik, const float* bik,
                       const float* Wiv, const float* biv, const float* Wq,  const float* bq,
                       const float* Wiq, const float* biq, float* ws){
  int t = blockIdx.x*256 + threadIdx.x;
  if (t < 36864){
    int r = t >> 8, c = t & 255;
    float a = 0.f;
    for (int m=0;m<256;m++) a += Wkv[(size_t)r*512+m] * Wik[(size_t)m*256+c];
    ws[F_WCK + t] = a;
  } else if (t < 37120){
    int c = t - 36864;
    float a = bik[c];
    for (int m=0;m<256;m++) a += bkv[m] * Wik[(size_t)m*256+c];
    ws[F_BCK + c] = a;
  } else if (t < 73984){
    int i = t - 37120; int r = i >> 8, c = i & 255;
    float a = 0.f;
    for (int m=0;m<256;m++) a += Wkv[(size_t)r*512+256+m] * Wiv[(size_t)m*256+c];
    ws[F_WCV + i] = a;
  } else if (t < 74240){
    int c = t - 73984;
    float a = biv[c];
    for (int m=0;m<256;m++) a += bkv[256+m] * Wiv[(size_t)m*256+c];
    ws[F_BCV + c] = a;
  } else if (t < 90624){
    int i = t - 74240; int r = i >> 8, c = i & 255;
    float a = 0.f;
    for (int m=0;m<256;m++) a += Wq[(size_t)r*256+m] * Wiq[(size_t)m*256+c];
    ws[F_WQ2 + i] = a;
  } else if (t < 90880){
    int c = t - 90624;
    float a = biq[c];
    for (int m=0;m<256;m++) a += bq[m] * Wiq[(size_t)m*256+c];
    ws[F_BQ2 + c] = a;
  }
}

// =============== node_feat = node_raw@Wn + bn ===============
__global__ void k_nf(const float* node_raw, const float* Wn, const float* bn, float* ws){
  size_t t = (size_t)blockIdx.x*256 + threadIdx.x;   // B*N*64 total
  int j = (int)(t & 63); size_t row = t >> 6;
  float a = bn[j];
  #pragma unroll
  for (int i=0;i<8;i++) a += node_raw[row*8+i] * Wn[(size_t)i*64+j];
  ws[F_NF + t] = a;
}

// =============== edge_feat = edge_raw@We + be ===============
__global__ void k_ef(const float* edge_raw, const float* We, const float* be, float* ws){
  size_t t = (size_t)blockIdx.x*256 + threadIdx.x;   // B*E*16 total
  int j = (int)(t & 15); size_t row = t >> 4;
  float a = be[j];
  #pragma unroll
  for (int i=0;i<3;i++) a += edge_raw[row*3+i] * We[(size_t)i*16+j];
  ws[F_EF + t] = a;
}

// =============== q[b] = ego@Wq2 + bq2 ===============
__global__ void k_q(const int* ego_p, float* ws){
  int b = blockIdx.x, c = threadIdx.x;
  int ego = *ego_p;
  const float* egf = ws + F_NF + ((size_t)b*NN + ego)*64;
  const float* Wq2 = ws + F_WQ2;
  float a = ws[F_BQ2 + c];
  for (int i=0;i<64;i++) a += egf[i]*Wq2[(size_t)i*256+c];
  ws[F_Q + (size_t)b*256 + c] = a;
}

// =============== per (b,h): aw (80) and c0 so score = (c0 + F·aw)/8 ===============
__global__ void k_head(const int* ego_p, float* ws){
  int b = blockIdx.x >> 2, h = blockIdx.x & 3;
  int tid = threadIdx.x;
  __shared__ float qh[64];
  __shared__ float red[256];
  if (tid < 64) qh[tid] = ws[F_Q + (size_t)b*256 + h*64 + tid];
  __syncthreads();
  const float* Wck = ws + F_WCK;
  float p = 0.f;
  size_t awbase = F_AW + ((size_t)(b*4+h))*80;
  if (tid < 64){                               // neighbor-part weights (ei rows 80..143)
    const float* wr = Wck + (size_t)(80+tid)*256 + h*64;
    float a=0.f; for(int d=0;d<64;d++) a += wr[d]*qh[d];
    ws[awbase + tid] = a;
  } else if (tid < 80){                        // edge-part weights (rows 64..79)
    int i = tid-64;
    const float* wr = Wck + (size_t)(64+i)*256 + h*64;
    float a=0.f; for(int d=0;d<64;d++) a += wr[d]*qh[d];
    ws[awbase + 64 + i] = a;
  } else if (tid < 144){                       // ego-part constant (rows 0..63)
    int j = tid-80;
    const float* wr = Wck + (size_t)j*256 + h*64;
    float a=0.f; for(int d=0;d<64;d++) a += wr[d]*qh[d];
    int ego = *ego_p;
    p = ws[F_NF + ((size_t)b*NN+ego)*64 + j] * a;
  } else if (tid < 208){                       // bias constant
    int d = tid-144;
    p = ws[F_BCK + h*64 + d] * qh[d];
  }
  red[tid]=p; __syncthreads();
  for (int s=128;s>0;s>>=1){ if(tid<s) red[tid]+=red[tid+s]; __syncthreads(); }
  if (tid==0) ws[F_C0 + b*4 + h] = red[0];
}

// =============== attention scores for all heads ===============
__global__ void k_scores(const int* ego_p, float* ws){
  int b = blockIdx.x, tid = threadIdx.x;
  __shared__ float awz[4][80];
  __shared__ float c0s[4];
  for (int l=tid; l<320; l+=256) awz[l/80][l%80] = ws[F_AW + (size_t)b*320 + l];
  if (tid<4) c0s[tid] = ws[F_C0 + b*4 + tid];
  __syncthreads();
  int ego = *ego_p;
  for (int e=tid; e<EE; e+=256){
    int node = e < ego ? e : e+1;
    const float4* nr = (const float4*)(ws + F_NF + ((size_t)b*NN+node)*64);
    const float4* er = (const float4*)(ws + F_EF + ((size_t)b*EE+e)*16);
    float s[4] = {c0s[0],c0s[1],c0s[2],c0s[3]};
    #pragma unroll
    for (int i=0;i<16;i++){
      float4 x = nr[i];
      #pragma unroll
      for (int h=0;h<4;h++)
        s[h] += x.x*awz[h][i*4] + x.y*awz[h][i*4+1] + x.z*awz[h][i*4+2] + x.w*awz[h][i*4+3];
    }
    #pragma unroll
    for (int i=0;i<4;i++){
      float4 x = er[i];
      #pragma unroll
      for (int h=0;h<4;h++)
        s[h] += x.x*awz[h][64+i*4] + x.y*awz[h][64+i*4+1] + x.z*awz[h][64+i*4+2] + x.w*awz[h][64+i*4+3];
    }
    #pragma unroll
    for (int h=0;h<4;h++) ws[F_SC + ((size_t)(b*4+h))*EE + e] = s[h]*0.125f;
  }
}

// =============== softmax over E per (b,h), in place ===============
__global__ void k_softmax(float* ws){
  int bh = blockIdx.x, tid = threadIdx.x;
  float* s = ws + F_SC + (size_t)bh*EE;
  __shared__ float red[256];
  float v0 = tid<EE ? s[tid] : -INFINITY;
  float v1 = tid+256<EE ? s[tid+256] : -INFINITY;
  red[tid] = fmaxf(v0,v1); __syncthreads();
  for (int st=128;st>0;st>>=1){ if(tid<st) red[tid]=fmaxf(red[tid],red[tid+st]); __syncthreads(); }
  float m = red[0]; __syncthreads();
  float e0 = tid<EE ? expf(v0-m) : 0.f;
  float e1 = tid+256<EE ? expf(v1-m) : 0.f;
  red[tid] = e0+e1; __syncthreads();
  for (int st=128;st>0;st>>=1){ if(tid<st) red[tid]+=red[tid+st]; __syncthreads(); }
  float inv = 1.f/red[0];
  if (tid<EE) s[tid] = e0*inv;
  if (tid+256<EE) s[tid+256] = e1*inv;
}

// =============== u[b,h,d] = sum_e attn * F[b,e,d]  (d<64: nbr, d>=64: ef) ===============
__global__ void k_usum(const int* ego_p, float* ws){
  int b = blockIdx.x>>2, h = blockIdx.x&3, d = threadIdx.x;
  if (d >= 80) return;
  const float* at = ws + F_SC + ((size_t)(b*4+h))*EE;
  int ego = *ego_p;
  float a = 0.f;
  if (d < 64){
    const float* base = ws + F_NF + (size_t)b*NN*64 + d;
    for (int e=0;e<EE;e++){
      int node = e<ego?e:e+1;
      a += at[e]*base[(size_t)node*64];
    }
  } else {
    const float* base = ws + F_EF + (size_t)b*EE*16 + (d-64);
    for (int e=0;e<EE;e++) a += at[e]*base[(size_t)e*16];
  }
  ws[F_US + ((size_t)(b*4+h))*80 + d] = a;
}

// =============== per-b tail: ctx -> c_ego -> h_ego_prime(out) + cvec ===============
__global__ void k_bfinal(const int* ego_p,
                         const float* Wo, const float* bo,
                         const float* Wf1, const float* bf1p,
                         const float* Wf2, const float* bf2p,
                         const float* Ws1, const float* bs1,
                         float* ws, float* out){
  int b = blockIdx.x, t = threadIdx.x;
  __shared__ float ego_s[64], us_s[4][80], ctx_s[256], cego_s[256], hf_s[256];
  int ego = *ego_p;
  if (t < 64) ego_s[t] = ws[F_NF + ((size_t)b*NN+ego)*64 + t];
  for (int l=t; l<320; l+=256) us_s[l/80][l%80] = ws[F_US + (size_t)b*320 + l];
  __syncthreads();
  {  // ctx = (sum attn * edge_input) @ Wcv + bcv
    int h = t >> 6;
    const float* Wcv = ws + F_WCV;
    float a = ws[F_BCV + t];
    for (int i=0;i<64;i++) a += ego_s[i]*Wcv[(size_t)i*256+t];
    for (int i=0;i<16;i++) a += us_s[h][64+i]*Wcv[(size_t)(64+i)*256+t];
    for (int i=0;i<64;i++) a += us_s[h][i]*Wcv[(size_t)(80+i)*256+t];
    ctx_s[t]=a;
  }
  __syncthreads();
  {  // c_ego = ctx @ Wo + bo
    float a = bo[t];
    for (int i=0;i<256;i++) a += ctx_s[i]*Wo[(size_t)i*256+t];
    cego_s[t]=a; ws[F_CEGO + (size_t)b*256+t]=a;
  }
  __syncthreads();
  {  // hf = relu([ego, c_ego] @ Wf1 + bf1)
    float a = bf1p[t];
    for (int i=0;i<64;i++)  a += ego_s[i]*Wf1[(size_t)i*256+t];
    for (int i=0;i<256;i++) a += cego_s[i]*Wf1[(size_t)(64+i)*256+t];
    hf_s[t]=fmaxf(a,0.f);
  }
  __syncthreads();
  {  // h_ego_prime = hf @ Wf2 + bf2
    float a = bf2p[t];
    for (int i=0;i<256;i++) a += hf_s[i]*Wf2[(size_t)i*256+t];
    out[O_HEGO + (size_t)b*256+t] = a;
  }
  {  // cvec = c_ego @ Ws1[80:336] + bs1
    float a = bs1[t];
    for (int i=0;i<256;i++) a += cego_s[i]*Ws1[(size_t)(80+i)*256+t];
    ws[F_CVEC + (size_t)b*256+t]=a;
  }
}

// =============== edge score GEMM: score[b,e] = relu(F@Ws1[:80]+cvec)·w2col0 + bs2[0] ===============
__global__ __launch_bounds__(256) void k_bigscore(const int* ego_p, const float* Ws1,
                                                  const float* Ws2, const float* bs2, float* ws){
  int tile = blockIdx.x, b = blockIdx.y;
  int tid = threadIdx.x;
  __shared__ float Ft[80][64];          // F^T for 64 edges
  __shared__ float cv_s[256], w2_s[256];
  cv_s[tid] = ws[F_CVEC + (size_t)b*256 + tid];
  w2_s[tid] = Ws2[(size_t)tid*1537];            // Ws2[:,0]
  int ego = *ego_p;
  for (int l=tid; l<80*64; l+=256){
    int e = l/80, k = l - e*80;
    int eg = tile*64 + e;
    float v = 0.f;
    if (eg < EE){
      int node = eg<ego?eg:eg+1;
      v = (k<64) ? ws[F_NF + ((size_t)b*NN+node)*64 + k]
                 : ws[F_EF + ((size_t)b*EE+eg)*16 + (k-64)];
    }
    Ft[k][e] = v;
  }
  __syncthreads();
  int tc = tid & 31, te = tid >> 5;     // te: edge group (8 edges), tc: col group (8 cols)
  float acc[8][8];
  #pragma unroll
  for (int i=0;i<8;i++)
    #pragma unroll
    for (int j=0;j<8;j++) acc[i][j]=0.f;
  for (int k=0;k<80;k++){
    float4 a0 = *(const float4*)&Ft[k][te*8];
    float4 a1 = *(const float4*)&Ft[k][te*8+4];
    float av[8] = {a0.x,a0.y,a0.z,a0.w,a1.x,a1.y,a1.z,a1.w};
    float4 b0 = *(const float4*)(Ws1 + (size_t)k*256 + tc*8);
    float4 b1 = *(const float4*)(Ws1 + (size_t)k*256 + tc*8 + 4);
    float bv[8] = {b0.x,b0.y,b0.z,b0.w,b1.x,b1.y,b1.z,b1.w};
    #pragma unroll
    for (int i=0;i<8;i++)
      #pragma unroll
      for (int j=0;j<8;j++) acc[i][j] = fmaf(av[i], bv[j], acc[i][j]);
  }
  float bs20 = bs2[0];
  #pragma unroll
  for (int i=0;i<8;i++){
    float p = 0.f;
    #pragma unroll
    for (int j=0;j<8;j++){
      float hcol = acc[i][j] + cv_s[tc*8+j];
      p += fmaxf(hcol,0.f)*w2_s[tc*8+j];
    }
    #pragma unroll
    for (int m=16;m>0;m>>=1) p += __shfl_xor(p, m, 64);
    if (tc==0){
      int eg = tile*64 + te*8 + i;
      if (eg < EE) ws[F_SC2 + (size_t)b*EE + eg] = p + bs20;
    }
  }
}

// =============== top-5 (stable, ties -> lower index) + alpha softmax ===============
__global__ void k_topk(float* ws, float* out){
  int b = blockIdx.x, tid = threadIdx.x;
  __shared__ float sv[256]; __shared__ int si[256];
  __shared__ float tv[8];   __shared__ int tix[8];
  const float* s = ws + F_SC2 + (size_t)b*EE;
  float v0 = tid<EE ? s[tid] : -INFINITY;       int i0 = tid;
  float v1 = (tid+256)<EE ? s[tid+256] : -INFINITY; int i1 = tid+256;
  for (int t=0;t<5;t++){
    float bvv; int bii;
    if (v0 > v1 || (v0==v1 && i0<i1)){ bvv=v0; bii=i0; } else { bvv=v1; bii=i1; }
    sv[tid]=bvv; si[tid]=bii; __syncthreads();
    for (int st=128; st>0; st>>=1){
      if (tid<st){
        float ov=sv[tid+st]; int oi=si[tid+st];
        if (ov > sv[tid] || (ov==sv[tid] && oi<si[tid])){ sv[tid]=ov; si[tid]=oi; }
      }
      __syncthreads();
    }
    if (tid==0){ tv[t]=sv[0]; tix[t]=si[0]; }
    __syncthreads();
    int w = tix[t];
    if (i0==w) v0=-INFINITY;
    if (i1==w) v1=-INFINITY;
    __syncthreads();
  }
  if (tid==0){
    float m = tv[0];
    float ex[5]; float sum=0.f;
    for (int t=0;t<5;t++){ ex[t]=expf(tv[t]-m); sum+=ex[t]; }
    for (int t=0;t<5;t++){
      float al = ex[t]/sum;
      ws[F_ALPHA + (size_t)b*5+t] = al;
      ((int*)(ws + F_TKI))[b*5+t] = tix[t];
      out[O_TKI   + (size_t)b*5+t] = (float)tix[t];
      out[O_ALPHA + (size_t)b*5+t] = al;
    }
  }
}

// =============== selected rows: recompute hidden, h_enc = hidden@Ws2[:,1:], * alpha ===============
__global__ void k_sel(const int* ego_p, const float* Ws1, const float* Ws2, const float* bs2,
                      float* ws, float* out){
  int b = blockIdx.x, tid = threadIdx.x;
  __shared__ float hs[5][256];
  __shared__ float al[5]; __shared__ int es[5];
  if (tid<5){ es[tid] = ((const int*)(ws+F_TKI))[b*5+tid]; al[tid]=ws[F_ALPHA+(size_t)b*5+tid]; }
  __syncthreads();
  int ego = *ego_p;
  float cv = ws[F_CVEC + (size_t)b*256 + tid];
  for (int t=0;t<5;t++){
    int e = es[t]; int node = e<ego?e:e+1;
    const float* nr = ws + F_NF + ((size_t)b*NN+node)*64;
    const float* er = ws + F_EF + ((size_t)b*EE+e)*16;
    float a = cv;
    for (int d=0;d<64;d++) a += nr[d]*Ws1[(size_t)d*256+tid];
    for (int d=0;d<16;d++) a += er[d]*Ws1[(size_t)(64+d)*256+tid];
    hs[t][tid] = fmaxf(a,0.f);
  }
  __syncthreads();
  for (int r=0;r<6;r++){
    int n = r*256 + tid;
    float a0=0.f,a1=0.f,a2=0.f,a3=0.f,a4=0.f;
    for (int j=0;j<256;j++){
      float w = Ws2[(size_t)j*1537 + 1 + n];
      a0 = fmaf(hs[0][j], w, a0);
      a1 = fmaf(hs[1][j], w, a1);
      a2 = fmaf(hs[2][j], w, a2);
      a3 = fmaf(hs[3][j], w, a3);
      a4 = fmaf(hs[4][j], w, a4);
    }
    float bb = bs2[1+n];
    out[O_SEL + ((size_t)(b*5+0))*1536 + n] = (a0+bb)*al[0];
    out[O_SEL + ((size_t)(b*5+1))*1536 + n] = (a1+bb)*al[1];
    out[O_SEL + ((size_t)(b*5+2))*1536 + n] = (a2+bb)*al[2];
    out[O_SEL + ((size_t)(b*5+3))*1536 + n] = (a3+bb)*al[3];
    out[O_SEL + ((size_t)(b*5+4))*1536 + n] = (a4+bb)*al[4];
  }
}

extern "C" void kernel_launch(void* const* d_in, const int* in_sizes, int n_in,
                              void* d_out, int out_size, void* d_ws, size_t ws_size,
                              hipStream_t stream){
  const float* node_raw=(const float*)d_in[0];
  const float* edge_raw=(const float*)d_in[1];
  const int*  ego_p   =(const int*)d_in[2];
  const float* Wn =(const float*)d_in[3];  const float* bn =(const float*)d_in[4];
  const float* We =(const float*)d_in[5];  const float* be =(const float*)d_in[6];
  const float* Wq =(const float*)d_in[7];  const float* bq =(const float*)d_in[8];
  const float* Wkv=(const float*)d_in[9];  const float* bkv=(const float*)d_in[10];
  const float* Wiq=(const float*)d_in[11]; const float* biq=(const float*)d_in[12];
  const float* Wik=(const float*)d_in[13]; const float* bik=(const float*)d_in[14];
  const float* Wiv=(const float*)d_in[15]; const float* biv=(const float*)d_in[16];
  const float* Wo =(const float*)d_in[17]; const float* bo =(const float*)d_in[18];
  const float* Wf1=(const float*)d_in[19]; const float* bf1p=(const float*)d_in[20];
  const float* Wf2=(const float*)d_in[21]; const float* bf2p=(const float*)d_in[22];
  const float* Ws1=(const float*)d_in[23]; const float* bs1=(const float*)d_in[24];
  const float* Ws2=(const float*)d_in[25]; const float* bs2=(const float*)d_in[26];
  float* ws=(float*)d_ws;
  float* out=(float*)d_out;

  k_fuse<<<355,256,0,stream>>>(Wkv,bkv,Wik,bik,Wiv,biv,Wq,bq,Wiq,biq,ws);
  k_nf<<<(B*NN*64)/256,256,0,stream>>>(node_raw,Wn,bn,ws);
  k_ef<<<(B*EE*16)/256,256,0,stream>>>(edge_raw,We,be,ws);
  k_q<<<B,256,0,stream>>>(ego_p,ws);
  k_head<<<B*4,256,0,stream>>>(ego_p,ws);
  k_scores<<<B,256,0,stream>>>(ego_p,ws);
  k_softmax<<<B*4,256,0,stream>>>(ws);
  k_usum<<<B*4,128,0,stream>>>(ego_p,ws);
  k_bfinal<<<B,256,0,stream>>>(ego_p,Wo,bo,Wf1,bf1p,Wf2,bf2p,Ws1,bs1,ws,out);
  k_bigscore<<<dim3(8,B),256,0,stream>>>(ego_p,Ws1,Ws2,bs2,ws);
  k_topk<<<B,256,0,stream>>>(ws,out);
  k_sel<<<B,256,0,stream>>>(ego_p,Ws1,Ws2,bs2,ws,out);
}

// Round 5
// 366.416 us; speedup vs baseline: 1.0956x; 1.0956x over previous
//
#include <hip/hip_runtime.h>
#include <hip/hip_bf16.h>
#include <math.h>

constexpr int B = 256, NN = 512, EE = 511;

// ---- workspace layout (fp32 element offsets) ----
constexpr size_t F_NF    = 0;                               // node_feat  B*N*64
constexpr size_t F_EF    = F_NF   + (size_t)B*NN*64;        // edge_feat  B*E*16
constexpr size_t F_WCK   = F_EF   + (size_t)B*EE*16;        // fused K weight 144x256
constexpr size_t F_BCK   = F_WCK  + 144*256;
constexpr size_t F_WCV   = F_BCK  + 256;                    // fused V weight 144x256
constexpr size_t F_BCV   = F_WCV  + 144*256;
constexpr size_t F_WQ2   = F_BCV  + 256;                    // fused Q weight 64x256
constexpr size_t F_BQ2   = F_WQ2  + 64*256;
constexpr size_t F_Q     = F_BQ2  + 256;                    // q  B*256
constexpr size_t F_AW    = F_Q    + (size_t)B*256;          // per (b,h) score weights 80
constexpr size_t F_C0    = F_AW   + (size_t)B*4*80;         // per (b,h) score const
constexpr size_t F_SC    = F_C0   + (size_t)B*4;            // scores/attn B*4*E (dead after k_usum)
constexpr size_t F_US    = F_SC   + (size_t)B*4*EE;         // weighted sums B*4*80
constexpr size_t F_CEGO  = F_US   + (size_t)B*4*80;         // c_ego B*256
constexpr size_t F_CVEC  = F_CEGO + (size_t)B*256;          // cvec  B*256
constexpr size_t F_SC2   = F_CVEC + (size_t)B*256;          // edge scores B*E
constexpr size_t F_ALPHA = F_SC2  + (size_t)B*EE;           // B*5
constexpr size_t F_TKI   = F_ALPHA+ (size_t)B*5;            // B*5 (ints)
constexpr size_t F_HS    = F_SC;                            // selected hidden B*5*256 (aliases dead F_SC)

// ---- output layout (fp32 elements) ----
constexpr size_t O_HEGO  = 0;          // B*256
constexpr size_t O_SEL   = 65536;      // B*5*6*256
constexpr size_t O_TKI   = 2031616;    // B*5
constexpr size_t O_ALPHA = 2032896;    // B*5

// =============== weight fusion: Wck=WkvK@Wik, Wcv=WkvV@Wiv, Wq2=Wq@Wiq ===============
__global__ void k_fuse(const float* Wkv, const float* bkv, const float* Wik, const float* bik,
                       const float* Wiv, const float* biv, const float* Wq,  const float* bq,
                       const float* Wiq, const float* biq, float* ws){
  int t = blockIdx.x*256 + threadIdx.x;
  if (t < 36864){
    int r = t >> 8, c = t & 255;
    float a = 0.f;
    for (int m=0;m<256;m++) a += Wkv[(size_t)r*512+m] * Wik[(size_t)m*256+c];
    ws[F_WCK + t] = a;
  } else if (t < 37120){
    int c = t - 36864;
    float a = bik[c];
    for (int m=0;m<256;m++) a += bkv[m] * Wik[(size_t)m*256+c];
    ws[F_BCK + c] = a;
  } else if (t < 73984){
    int i = t - 37120; int r = i >> 8, c = i & 255;
    float a = 0.f;
    for (int m=0;m<256;m++) a += Wkv[(size_t)r*512+256+m] * Wiv[(size_t)m*256+c];
    ws[F_WCV + i] = a;
  } else if (t < 74240){
    int c = t - 73984;
    float a = biv[c];
    for (int m=0;m<256;m++) a += bkv[256+m] * Wiv[(size_t)m*256+c];
    ws[F_BCV + c] = a;
  } else if (t < 90624){
    int i = t - 74240; int r = i >> 8, c = i & 255;
    float a = 0.f;
    for (int m=0;m<256;m++) a += Wq[(size_t)r*256+m] * Wiq[(size_t)m*256+c];
    ws[F_WQ2 + i] = a;
  } else if (t < 90880){
    int c = t - 90624;
    float a = biq[c];
    for (int m=0;m<256;m++) a += bq[m] * Wiq[(size_t)m*256+c];
    ws[F_BQ2 + c] = a;
  }
}

// =============== node_feat = node_raw@Wn + bn ===============
__global__ void k_nf(const float* node_raw, const float* Wn, const float* bn, float* ws){
  size_t t = (size_t)blockIdx.x*256 + threadIdx.x;   // B*N*64 total
  int j = (int)(t & 63); size_t row = t >> 6;
  float a = bn[j];
  #pragma unroll
  for (int i=0;i<8;i++) a += node_raw[row*8+i] * Wn[(size_t)i*64+j];
  ws[F_NF + t] = a;
}

// =============== edge_feat = edge_raw@We + be ===============
__global__ void k_ef(const float* edge_raw, const float* We, const float* be, float* ws){
  size_t t = (size_t)blockIdx.x*256 + threadIdx.x;   // B*E*16 total
  int j = (int)(t & 15); size_t row = t >> 4;
  float a = be[j];
  #pragma unroll
  for (int i=0;i<3;i++) a += edge_raw[row*3+i] * We[(size_t)i*16+j];
  ws[F_EF + t] = a;
}

// =============== q[b] = ego@Wq2 + bq2 ===============
__global__ void k_q(const int* ego_p, float* ws){
  int b = blockIdx.x, c = threadIdx.x;
  int ego = *ego_p;
  const float* egf = ws + F_NF + ((size_t)b*NN + ego)*64;
  const float* Wq2 = ws + F_WQ2;
  float a = ws[F_BQ2 + c];
  for (int i=0;i<64;i++) a += egf[i]*Wq2[(size_t)i*256+c];
  ws[F_Q + (size_t)b*256 + c] = a;
}

// =============== per (b,h): aw (80) and c0 so score = (c0 + F·aw)/8 ===============
__global__ void k_head(const int* ego_p, float* ws){
  int b = blockIdx.x >> 2, h = blockIdx.x & 3;
  int tid = threadIdx.x;
  __shared__ float qh[64];
  __shared__ float red[256];
  if (tid < 64) qh[tid] = ws[F_Q + (size_t)b*256 + h*64 + tid];
  __syncthreads();
  const float* Wck = ws + F_WCK;
  float p = 0.f;
  size_t awbase = F_AW + ((size_t)(b*4+h))*80;
  if (tid < 64){                               // neighbor-part weights (ei rows 80..143)
    const float* wr = Wck + (size_t)(80+tid)*256 + h*64;
    float a=0.f; for(int d=0;d<64;d++) a += wr[d]*qh[d];
    ws[awbase + tid] = a;
  } else if (tid < 80){                        // edge-part weights (rows 64..79)
    int i = tid-64;
    const float* wr = Wck + (size_t)(64+i)*256 + h*64;
    float a=0.f; for(int d=0;d<64;d++) a += wr[d]*qh[d];
    ws[awbase + 64 + i] = a;
  } else if (tid < 144){                       // ego-part constant (rows 0..63)
    int j = tid-80;
    const float* wr = Wck + (size_t)j*256 + h*64;
    float a=0.f; for(int d=0;d<64;d++) a += wr[d]*qh[d];
    int ego = *ego_p;
    p = ws[F_NF + ((size_t)b*NN+ego)*64 + j] * a;
  } else if (tid < 208){                       // bias constant
    int d = tid-144;
    p = ws[F_BCK + h*64 + d] * qh[d];
  }
  red[tid]=p; __syncthreads();
  for (int s=128;s>0;s>>=1){ if(tid<s) red[tid]+=red[tid+s]; __syncthreads(); }
  if (tid==0) ws[F_C0 + b*4 + h] = red[0];
}

// =============== attention scores for all heads ===============
__global__ void k_scores(const int* ego_p, float* ws){
  int b = blockIdx.x, tid = threadIdx.x;
  __shared__ float awz[4][80];
  __shared__ float c0s[4];
  for (int l=tid; l<320; l+=256) awz[l/80][l%80] = ws[F_AW + (size_t)b*320 + l];
  if (tid<4) c0s[tid] = ws[F_C0 + b*4 + tid];
  __syncthreads();
  int ego = *ego_p;
  for (int e=tid; e<EE; e+=256){
    int node = e < ego ? e : e+1;
    const float4* nr = (const float4*)(ws + F_NF + ((size_t)b*NN+node)*64);
    const float4* er = (const float4*)(ws + F_EF + ((size_t)b*EE+e)*16);
    float s[4] = {c0s[0],c0s[1],c0s[2],c0s[3]};
    #pragma unroll
    for (int i=0;i<16;i++){
      float4 x = nr[i];
      #pragma unroll
      for (int h=0;h<4;h++)
        s[h] += x.x*awz[h][i*4] + x.y*awz[h][i*4+1] + x.z*awz[h][i*4+2] + x.w*awz[h][i*4+3];
    }
    #pragma unroll
    for (int i=0;i<4;i++){
      float4 x = er[i];
      #pragma unroll
      for (int h=0;h<4;h++)
        s[h] += x.x*awz[h][64+i*4] + x.y*awz[h][64+i*4+1] + x.z*awz[h][64+i*4+2] + x.w*awz[h][64+i*4+3];
    }
    #pragma unroll
    for (int h=0;h<4;h++) ws[F_SC + ((size_t)(b*4+h))*EE + e] = s[h]*0.125f;
  }
}

// =============== softmax over E per (b,h), in place ===============
__global__ void k_softmax(float* ws){
  int bh = blockIdx.x, tid = threadIdx.x;
  float* s = ws + F_SC + (size_t)bh*EE;
  __shared__ float red[256];
  float v0 = tid<EE ? s[tid] : -INFINITY;
  float v1 = tid+256<EE ? s[tid+256] : -INFINITY;
  red[tid] = fmaxf(v0,v1); __syncthreads();
  for (int st=128;st>0;st>>=1){ if(tid<st) red[tid]=fmaxf(red[tid],red[tid+st]); __syncthreads(); }
  float m = red[0]; __syncthreads();
  float e0 = tid<EE ? expf(v0-m) : 0.f;
  float e1 = tid+256<EE ? expf(v1-m) : 0.f;
  red[tid] = e0+e1; __syncthreads();
  for (int st=128;st>0;st>>=1){ if(tid<st) red[tid]+=red[tid+st]; __syncthreads(); }
  float inv = 1.f/red[0];
  if (tid<EE) s[tid] = e0*inv;
  if (tid+256<EE) s[tid+256] = e1*inv;
}

// =============== u[b,h,d] = sum_e attn * F[b,e,d]  (d<64: nbr, d>=64: ef) ===============
__global__ void k_usum(const int* ego_p, float* ws){
  int b = blockIdx.x>>2, h = blockIdx.x&3, d = threadIdx.x;
  if (d >= 80) return;
  const float* at = ws + F_SC + ((size_t)(b*4+h))*EE;
  int ego = *ego_p;
  float a = 0.f;
  if (d < 64){
    const float* base = ws + F_NF + (size_t)b*NN*64 + d;
    for (int e=0;e<EE;e++){
      int node = e<ego?e:e+1;
      a += at[e]*base[(size_t)node*64];
    }
  } else {
    const float* base = ws + F_EF + (size_t)b*EE*16 + (d-64);
    for (int e=0;e<EE;e++) a += at[e]*base[(size_t)e*16];
  }
  ws[F_US + ((size_t)(b*4+h))*80 + d] = a;
}

// =============== per-b tail: ctx -> c_ego -> h_ego_prime(out) + cvec ===============
__global__ void k_bfinal(const int* ego_p,
                         const float* Wo, const float* bo,
                         const float* Wf1, const float* bf1p,
                         const float* Wf2, const float* bf2p,
                         const float* Ws1, const float* bs1,
                         float* ws, float* out){
  int b = blockIdx.x, t = threadIdx.x;
  __shared__ float ego_s[64], us_s[4][80], ctx_s[256], cego_s[256], hf_s[256];
  int ego = *ego_p;
  if (t < 64) ego_s[t] = ws[F_NF + ((size_t)b*NN+ego)*64 + t];
  for (int l=t; l<320; l+=256) us_s[l/80][l%80] = ws[F_US + (size_t)b*320 + l];
  __syncthreads();
  {  // ctx = (sum attn * edge_input) @ Wcv + bcv
    int h = t >> 6;
    const float* Wcv = ws + F_WCV;
    float a = ws[F_BCV + t];
    for (int i=0;i<64;i++) a += ego_s[i]*Wcv[(size_t)i*256+t];
    for (int i=0;i<16;i++) a += us_s[h][64+i]*Wcv[(size_t)(64+i)*256+t];
    for (int i=0;i<64;i++) a += us_s[h][i]*Wcv[(size_t)(80+i)*256+t];
    ctx_s[t]=a;
  }
  __syncthreads();
  {  // c_ego = ctx @ Wo + bo
    float a = bo[t];
    for (int i=0;i<256;i++) a += ctx_s[i]*Wo[(size_t)i*256+t];
    cego_s[t]=a; ws[F_CEGO + (size_t)b*256+t]=a;
  }
  __syncthreads();
  {  // hf = relu([ego, c_ego] @ Wf1 + bf1)
    float a = bf1p[t];
    for (int i=0;i<64;i++)  a += ego_s[i]*Wf1[(size_t)i*256+t];
    for (int i=0;i<256;i++) a += cego_s[i]*Wf1[(size_t)(64+i)*256+t];
    hf_s[t]=fmaxf(a,0.f);
  }
  __syncthreads();
  {  // h_ego_prime = hf @ Wf2 + bf2
    float a = bf2p[t];
    for (int i=0;i<256;i++) a += hf_s[i]*Wf2[(size_t)i*256+t];
    out[O_HEGO + (size_t)b*256+t] = a;
  }
  {  // cvec = c_ego @ Ws1[80:336] + bs1
    float a = bs1[t];
    for (int i=0;i<256;i++) a += cego_s[i]*Ws1[(size_t)(80+i)*256+t];
    ws[F_CVEC + (size_t)b*256+t]=a;
  }
}

// =============== edge score GEMM: score[b,e] = relu(F@Ws1[:80]+cvec)·w2col0 + bs2[0] ===============
__global__ __launch_bounds__(256) void k_bigscore(const int* ego_p, const float* Ws1,
                                                  const float* Ws2, const float* bs2, float* ws){
  int tile = blockIdx.x, b = blockIdx.y;
  int tid = threadIdx.x;
  __shared__ float Ft[80][64];          // F^T for 64 edges
  __shared__ float cv_s[256], w2_s[256];
  cv_s[tid] = ws[F_CVEC + (size_t)b*256 + tid];
  w2_s[tid] = Ws2[(size_t)tid*1537];            // Ws2[:,0]
  int ego = *ego_p;
  for (int l=tid; l<80*64; l+=256){
    int e = l/80, k = l - e*80;
    int eg = tile*64 + e;
    float v = 0.f;
    if (eg < EE){
      int node = eg<ego?eg:eg+1;
      v = (k<64) ? ws[F_NF + ((size_t)b*NN+node)*64 + k]
                 : ws[F_EF + ((size_t)b*EE+eg)*16 + (k-64)];
    }
    Ft[k][e] = v;
  }
  __syncthreads();
  int tc = tid & 31, te = tid >> 5;     // te: edge group (8 edges), tc: col group (8 cols)
  float acc[8][8];
  #pragma unroll
  for (int i=0;i<8;i++)
    #pragma unroll
    for (int j=0;j<8;j++) acc[i][j]=0.f;
  for (int k=0;k<80;k++){
    float4 a0 = *(const float4*)&Ft[k][te*8];
    float4 a1 = *(const float4*)&Ft[k][te*8+4];
    float av[8] = {a0.x,a0.y,a0.z,a0.w,a1.x,a1.y,a1.z,a1.w};
    float4 b0 = *(const float4*)(Ws1 + (size_t)k*256 + tc*8);
    float4 b1 = *(const float4*)(Ws1 + (size_t)k*256 + tc*8 + 4);
    float bv[8] = {b0.x,b0.y,b0.z,b0.w,b1.x,b1.y,b1.z,b1.w};
    #pragma unroll
    for (int i=0;i<8;i++)
      #pragma unroll
      for (int j=0;j<8;j++) acc[i][j] = fmaf(av[i], bv[j], acc[i][j]);
  }
  float bs20 = bs2[0];
  #pragma unroll
  for (int i=0;i<8;i++){
    float p = 0.f;
    #pragma unroll
    for (int j=0;j<8;j++){
      float hcol = acc[i][j] + cv_s[tc*8+j];
      p += fmaxf(hcol,0.f)*w2_s[tc*8+j];
    }
    #pragma unroll
    for (int m=16;m>0;m>>=1) p += __shfl_xor(p, m, 64);
    if (tc==0){
      int eg = tile*64 + te*8 + i;
      if (eg < EE) ws[F_SC2 + (size_t)b*EE + eg] = p + bs20;
    }
  }
}

// =============== top-5 (stable, ties -> lower index) + alpha softmax ===============
__global__ void k_topk(float* ws, float* out){
  int b = blockIdx.x, tid = threadIdx.x;
  __shared__ float sv[256]; __shared__ int si[256];
  __shared__ float tv[8];   __shared__ int tix[8];
  const float* s = ws + F_SC2 + (size_t)b*EE;
  float v0 = tid<EE ? s[tid] : -INFINITY;       int i0 = tid;
  float v1 = (tid+256)<EE ? s[tid+256] : -INFINITY; int i1 = tid+256;
  for (int t=0;t<5;t++){
    float bvv; int bii;
    if (v0 > v1 || (v0==v1 && i0<i1)){ bvv=v0; bii=i0; } else { bvv=v1; bii=i1; }
    sv[tid]=bvv; si[tid]=bii; __syncthreads();
    for (int st=128; st>0; st>>=1){
      if (tid<st){
        float ov=sv[tid+st]; int oi=si[tid+st];
        if (ov > sv[tid] || (ov==sv[tid] && oi<si[tid])){ sv[tid]=ov; si[tid]=oi; }
      }
      __syncthreads();
    }
    if (tid==0){ tv[t]=sv[0]; tix[t]=si[0]; }
    __syncthreads();
    int w = tix[t];
    if (i0==w) v0=-INFINITY;
    if (i1==w) v1=-INFINITY;
    __syncthreads();
  }
  if (tid==0){
    float m = tv[0];
    float ex[5]; float sum=0.f;
    for (int t=0;t<5;t++){ ex[t]=expf(tv[t]-m); sum+=ex[t]; }
    for (int t=0;t<5;t++){
      float al = ex[t]/sum;
      ws[F_ALPHA + (size_t)b*5+t] = al;
      ((int*)(ws + F_TKI))[b*5+t] = tix[t];
      out[O_TKI   + (size_t)b*5+t] = (float)tix[t];
      out[O_ALPHA + (size_t)b*5+t] = al;
    }
  }
}

// =============== selected hidden rows: hs[b,t,:] = relu(F_sel@Ws1[:80] + cvec) ===============
__global__ void k_hid(const int* ego_p, const float* Ws1, float* ws){
  int bt = blockIdx.x;               // b*5 + t
  int b = bt/5;
  int tid = threadIdx.x;
  __shared__ float fr[80];
  int e = ((const int*)(ws+F_TKI))[bt];
  int ego = *ego_p;
  int node = e<ego ? e : e+1;
  if (tid < 64)      fr[tid] = ws[F_NF + ((size_t)b*NN+node)*64 + tid];
  else if (tid < 80) fr[tid] = ws[F_EF + ((size_t)b*EE+e)*16 + (tid-64)];
  __syncthreads();
  float a = ws[F_CVEC + (size_t)b*256 + tid];
  for (int d=0;d<80;d++) a += fr[d]*Ws1[(size_t)d*256+tid];
  ws[F_HS + (size_t)bt*256 + tid] = fmaxf(a,0.f);
}

// =============== h_enc GEMM: out_sel[b,t,n] = (hs[b,t,:]·Ws2[:,1+n] + bs2[1+n])*alpha ===============
// grid (3, 64): r = 512-col chunk, g = group of 4 batches. Each thread: 2 cols x 20 rows.
__global__ __launch_bounds__(256) void k_enc(const float* Ws2, const float* bs2,
                                             float* ws, float* out){
  int r = blockIdx.x, g = blockIdx.y, tid = threadIdx.x;
  int n0 = r*512 + tid, n1 = n0 + 256;
  __shared__ float hs[20][256];
  __shared__ float al[20];
  int b0 = g*4;
  for (int l=tid; l<20*256; l+=256)
    hs[l>>8][l&255] = ws[F_HS + ((size_t)b0*5 + (l>>8))*256 + (l&255)];
  if (tid<20) al[tid] = ws[F_ALPHA + (size_t)b0*5 + tid];
  __syncthreads();
  float a0[20], a1[20];
  #pragma unroll
  for (int i=0;i<20;i++){ a0[i]=0.f; a1[i]=0.f; }
  for (int j=0;j<256;j+=4){
    float w00=Ws2[(size_t)(j+0)*1537+1+n0], w01=Ws2[(size_t)(j+0)*1537+1+n1];
    float w10=Ws2[(size_t)(j+1)*1537+1+n0], w11=Ws2[(size_t)(j+1)*1537+1+n1];
    float w20=Ws2[(size_t)(j+2)*1537+1+n0], w21=Ws2[(size_t)(j+2)*1537+1+n1];
    float w30=Ws2[(size_t)(j+3)*1537+1+n0], w31=Ws2[(size_t)(j+3)*1537+1+n1];
    #pragma unroll
    for (int i=0;i<20;i++){
      float4 h = *(const float4*)&hs[i][j];
      a0[i] = fmaf(h.x,w00, fmaf(h.y,w10, fmaf(h.z,w20, fmaf(h.w,w30, a0[i]))));
      a1[i] = fmaf(h.x,w01, fmaf(h.y,w11, fmaf(h.z,w21, fmaf(h.w,w31, a1[i]))));
    }
  }
  float bb0 = bs2[1+n0], bb1 = bs2[1+n1];
  #pragma unroll
  for (int i=0;i<20;i++){
    out[O_SEL + ((size_t)(b0*5+i))*1536 + n0] = (a0[i]+bb0)*al[i];
    out[O_SEL + ((size_t)(b0*5+i))*1536 + n1] = (a1[i]+bb1)*al[i];
  }
}

extern "C" void kernel_launch(void* const* d_in, const int* in_sizes, int n_in,
                              void* d_out, int out_size, void* d_ws, size_t ws_size,
                              hipStream_t stream){
  const float* node_raw=(const float*)d_in[0];
  const float* edge_raw=(const float*)d_in[1];
  const int*  ego_p   =(const int*)d_in[2];
  const float* Wn =(const float*)d_in[3];  const float* bn =(const float*)d_in[4];
  const float* We =(const float*)d_in[5];  const float* be =(const float*)d_in[6];
  const float* Wq =(const float*)d_in[7];  const float* bq =(const float*)d_in[8];
  const float* Wkv=(const float*)d_in[9];  const float* bkv=(const float*)d_in[10];
  const float* Wiq=(const float*)d_in[11]; const float* biq=(const float*)d_in[12];
  const float* Wik=(const float*)d_in[13]; const float* bik=(const float*)d_in[14];
  const float* Wiv=(const float*)d_in[15]; const float* biv=(const float*)d_in[16];
  const float* Wo =(const float*)d_in[17]; const float* bo =(const float*)d_in[18];
  const float* Wf1=(const float*)d_in[19]; const float* bf1p=(const float*)d_in[20];
  const float* Wf2=(const float*)d_in[21]; const float* bf2p=(const float*)d_in[22];
  const float* Ws1=(const float*)d_in[23]; const float* bs1=(const float*)d_in[24];
  const float* Ws2=(const float*)d_in[25]; const float* bs2=(const float*)d_in[26];
  float* ws=(float*)d_ws;
  float* out=(float*)d_out;

  k_fuse<<<355,256,0,stream>>>(Wkv,bkv,Wik,bik,Wiv,biv,Wq,bq,Wiq,biq,ws);
  k_nf<<<(B*NN*64)/256,256,0,stream>>>(node_raw,Wn,bn,ws);
  k_ef<<<(B*EE*16)/256,256,0,stream>>>(edge_raw,We,be,ws);
  k_q<<<B,256,0,stream>>>(ego_p,ws);
  k_head<<<B*4,256,0,stream>>>(ego_p,ws);
  k_scores<<<B,256,0,stream>>>(ego_p,ws);
  k_softmax<<<B*4,256,0,stream>>>(ws);
  k_usum<<<B*4,128,0,stream>>>(ego_p,ws);
  k_bfinal<<<B,256,0,stream>>>(ego_p,Wo,bo,Wf1,bf1p,Wf2,bf2p,Ws1,bs1,ws,out);
  k_bigscore<<<dim3(8,B),256,0,stream>>>(ego_p,Ws1,Ws2,bs2,ws);
  k_topk<<<B,256,0,stream>>>(ws,out);
  k_hid<<<B*5,256,0,stream>>>(ego_p,Ws1,ws);
  k_enc<<<dim3(3,64),256,0,stream>>>(Ws2,bs2,ws,out);
}

// Round 6
// 291.626 us; speedup vs baseline: 1.3766x; 1.2565x over previous
//
#include <hip/hip_runtime.h>
#include <hip/hip_bf16.h>
#include <math.h>

constexpr int B = 256, NN = 512, EE = 511;

// ---- workspace layout (fp32 element offsets) ----
constexpr size_t F_NF    = 0;                               // node_feat  B*N*64
constexpr size_t F_EF    = F_NF   + (size_t)B*NN*64;        // edge_feat  B*E*16
constexpr size_t F_WCK   = F_EF   + (size_t)B*EE*16;        // fused K weight 144x256
constexpr size_t F_BCK   = F_WCK  + 144*256;
constexpr size_t F_WCV   = F_BCK  + 256;                    // fused V weight 144x256
constexpr size_t F_BCV   = F_WCV  + 144*256;
constexpr size_t F_WQ2   = F_BCV  + 256;                    // fused Q weight 64x256
constexpr size_t F_BQ2   = F_WQ2  + 64*256;
constexpr size_t F_Q     = F_BQ2  + 256;                    // q  B*256
constexpr size_t F_AW    = F_Q    + (size_t)B*256;          // per (b,h) score weights 80
constexpr size_t F_C0    = F_AW   + (size_t)B*4*80;         // per (b,h) score const
constexpr size_t F_SC    = F_C0   + (size_t)B*4;            // scores/attn B*4*E (dead after k_usum)
constexpr size_t F_US    = F_SC   + (size_t)B*4*EE;         // weighted sums B*4*80
constexpr size_t F_CEGO  = F_US   + (size_t)B*4*80;         // c_ego B*256
constexpr size_t F_CVEC  = F_CEGO + (size_t)B*256;          // cvec  B*256
constexpr size_t F_SC2   = F_CVEC + (size_t)B*256;          // edge scores B*E
constexpr size_t F_ALPHA = F_SC2  + (size_t)B*EE;           // B*5
constexpr size_t F_TKI   = F_ALPHA+ (size_t)B*5;            // B*5 (ints)
constexpr size_t F_HS    = F_SC;                            // selected hidden B*5*256 (aliases dead F_SC)

// ---- output layout (fp32 elements) ----
constexpr size_t O_HEGO  = 0;          // B*256
constexpr size_t O_SEL   = 65536;      // B*5*6*256
constexpr size_t O_TKI   = 2031616;    // B*5
constexpr size_t O_ALPHA = 2032896;    // B*5

// =============== weight fusion: Wck=WkvK@Wik, Wcv=WkvV@Wiv, Wq2=Wq@Wiq ===============
__global__ void k_fuse(const float* Wkv, const float* bkv, const float* Wik, const float* bik,
                       const float* Wiv, const float* biv, const float* Wq,  const float* bq,
                       const float* Wiq, const float* biq, float* ws){
  int t = blockIdx.x*256 + threadIdx.x;
  if (t < 36864){
    int r = t >> 8, c = t & 255;
    float a = 0.f;
    for (int m=0;m<256;m++) a += Wkv[(size_t)r*512+m] * Wik[(size_t)m*256+c];
    ws[F_WCK + t] = a;
  } else if (t < 37120){
    int c = t - 36864;
    float a = bik[c];
    for (int m=0;m<256;m++) a += bkv[m] * Wik[(size_t)m*256+c];
    ws[F_BCK + c] = a;
  } else if (t < 73984){
    int i = t - 37120; int r = i >> 8, c = i & 255;
    float a = 0.f;
    for (int m=0;m<256;m++) a += Wkv[(size_t)r*512+256+m] * Wiv[(size_t)m*256+c];
    ws[F_WCV + i] = a;
  } else if (t < 74240){
    int c = t - 73984;
    float a = biv[c];
    for (int m=0;m<256;m++) a += bkv[256+m] * Wiv[(size_t)m*256+c];
    ws[F_BCV + c] = a;
  } else if (t < 90624){
    int i = t - 74240; int r = i >> 8, c = i & 255;
    float a = 0.f;
    for (int m=0;m<256;m++) a += Wq[(size_t)r*256+m] * Wiq[(size_t)m*256+c];
    ws[F_WQ2 + i] = a;
  } else if (t < 90880){
    int c = t - 90624;
    float a = biq[c];
    for (int m=0;m<256;m++) a += bq[m] * Wiq[(size_t)m*256+c];
    ws[F_BQ2 + c] = a;
  }
}

// =============== node_feat = node_raw@Wn + bn ===============
__global__ void k_nf(const float* node_raw, const float* Wn, const float* bn, float* ws){
  size_t t = (size_t)blockIdx.x*256 + threadIdx.x;   // B*N*64 total
  int j = (int)(t & 63); size_t row = t >> 6;
  float a = bn[j];
  #pragma unroll
  for (int i=0;i<8;i++) a += node_raw[row*8+i] * Wn[(size_t)i*64+j];
  ws[F_NF + t] = a;
}

// =============== edge_feat = edge_raw@We + be ===============
__global__ void k_ef(const float* edge_raw, const float* We, const float* be, float* ws){
  size_t t = (size_t)blockIdx.x*256 + threadIdx.x;   // B*E*16 total
  int j = (int)(t & 15); size_t row = t >> 4;
  float a = be[j];
  #pragma unroll
  for (int i=0;i<3;i++) a += edge_raw[row*3+i] * We[(size_t)i*16+j];
  ws[F_EF + t] = a;
}

// =============== q[b] = ego@Wq2 + bq2 ===============
__global__ void k_q(const int* ego_p, float* ws){
  int b = blockIdx.x, c = threadIdx.x;
  int ego = *ego_p;
  const float* egf = ws + F_NF + ((size_t)b*NN + ego)*64;
  const float* Wq2 = ws + F_WQ2;
  float a = ws[F_BQ2 + c];
  for (int i=0;i<64;i++) a += egf[i]*Wq2[(size_t)i*256+c];
  ws[F_Q + (size_t)b*256 + c] = a;
}

// =============== per (b,h): aw (80) and c0 so score = (c0 + F·aw)/8 ===============
__global__ void k_head(const int* ego_p, float* ws){
  int b = blockIdx.x >> 2, h = blockIdx.x & 3;
  int tid = threadIdx.x;
  __shared__ float qh[64];
  __shared__ float red[256];
  if (tid < 64) qh[tid] = ws[F_Q + (size_t)b*256 + h*64 + tid];
  __syncthreads();
  const float* Wck = ws + F_WCK;
  float p = 0.f;
  size_t awbase = F_AW + ((size_t)(b*4+h))*80;
  if (tid < 64){                               // neighbor-part weights (ei rows 80..143)
    const float* wr = Wck + (size_t)(80+tid)*256 + h*64;
    float a=0.f; for(int d=0;d<64;d++) a += wr[d]*qh[d];
    ws[awbase + tid] = a;
  } else if (tid < 80){                        // edge-part weights (rows 64..79)
    int i = tid-64;
    const float* wr = Wck + (size_t)(64+i)*256 + h*64;
    float a=0.f; for(int d=0;d<64;d++) a += wr[d]*qh[d];
    ws[awbase + 64 + i] = a;
  } else if (tid < 144){                       // ego-part constant (rows 0..63)
    int j = tid-80;
    const float* wr = Wck + (size_t)j*256 + h*64;
    float a=0.f; for(int d=0;d<64;d++) a += wr[d]*qh[d];
    int ego = *ego_p;
    p = ws[F_NF + ((size_t)b*NN+ego)*64 + j] * a;
  } else if (tid < 208){                       // bias constant
    int d = tid-144;
    p = ws[F_BCK + h*64 + d] * qh[d];
  }
  red[tid]=p; __syncthreads();
  for (int s=128;s>0;s>>=1){ if(tid<s) red[tid]+=red[tid+s]; __syncthreads(); }
  if (tid==0) ws[F_C0 + b*4 + h] = red[0];
}

// =============== attention scores for all heads ===============
__global__ void k_scores(const int* ego_p, float* ws){
  int b = blockIdx.x, tid = threadIdx.x;
  __shared__ float awz[4][80];
  __shared__ float c0s[4];
  for (int l=tid; l<320; l+=256) awz[l/80][l%80] = ws[F_AW + (size_t)b*320 + l];
  if (tid<4) c0s[tid] = ws[F_C0 + b*4 + tid];
  __syncthreads();
  int ego = *ego_p;
  for (int e=tid; e<EE; e+=256){
    int node = e < ego ? e : e+1;
    const float4* nr = (const float4*)(ws + F_NF + ((size_t)b*NN+node)*64);
    const float4* er = (const float4*)(ws + F_EF + ((size_t)b*EE+e)*16);
    float s[4] = {c0s[0],c0s[1],c0s[2],c0s[3]};
    #pragma unroll
    for (int i=0;i<16;i++){
      float4 x = nr[i];
      #pragma unroll
      for (int h=0;h<4;h++)
        s[h] += x.x*awz[h][i*4] + x.y*awz[h][i*4+1] + x.z*awz[h][i*4+2] + x.w*awz[h][i*4+3];
    }
    #pragma unroll
    for (int i=0;i<4;i++){
      float4 x = er[i];
      #pragma unroll
      for (int h=0;h<4;h++)
        s[h] += x.x*awz[h][64+i*4] + x.y*awz[h][64+i*4+1] + x.z*awz[h][64+i*4+2] + x.w*awz[h][64+i*4+3];
    }
    #pragma unroll
    for (int h=0;h<4;h++) ws[F_SC + ((size_t)(b*4+h))*EE + e] = s[h]*0.125f;
  }
}

// =============== softmax over E per (b,h), in place ===============
__global__ void k_softmax(float* ws){
  int bh = blockIdx.x, tid = threadIdx.x;
  float* s = ws + F_SC + (size_t)bh*EE;
  __shared__ float red[256];
  float v0 = tid<EE ? s[tid] : -INFINITY;
  float v1 = tid+256<EE ? s[tid+256] : -INFINITY;
  red[tid] = fmaxf(v0,v1); __syncthreads();
  for (int st=128;st>0;st>>=1){ if(tid<st) red[tid]=fmaxf(red[tid],red[tid+st]); __syncthreads(); }
  float m = red[0]; __syncthreads();
  float e0 = tid<EE ? expf(v0-m) : 0.f;
  float e1 = tid+256<EE ? expf(v1-m) : 0.f;
  red[tid] = e0+e1; __syncthreads();
  for (int st=128;st>0;st>>=1){ if(tid<st) red[tid]+=red[tid+st]; __syncthreads(); }
  float inv = 1.f/red[0];
  if (tid<EE) s[tid] = e0*inv;
  if (tid+256<EE) s[tid+256] = e1*inv;
}

// =============== u[b,h,d] = sum_e attn * F[b,e,d]  (d<64: nbr, d>=64: ef) ===============
__global__ void k_usum(const int* ego_p, float* ws){
  int b = blockIdx.x>>2, h = blockIdx.x&3, d = threadIdx.x;
  if (d >= 80) return;
  const float* at = ws + F_SC + ((size_t)(b*4+h))*EE;
  int ego = *ego_p;
  float a = 0.f;
  if (d < 64){
    const float* base = ws + F_NF + (size_t)b*NN*64 + d;
    for (int e=0;e<EE;e++){
      int node = e<ego?e:e+1;
      a += at[e]*base[(size_t)node*64];
    }
  } else {
    const float* base = ws + F_EF + (size_t)b*EE*16 + (d-64);
    for (int e=0;e<EE;e++) a += at[e]*base[(size_t)e*16];
  }
  ws[F_US + ((size_t)(b*4+h))*80 + d] = a;
}

// =============== per-b tail: ctx -> c_ego -> h_ego_prime(out) + cvec ===============
__global__ void k_bfinal(const int* ego_p,
                         const float* Wo, const float* bo,
                         const float* Wf1, const float* bf1p,
                         const float* Wf2, const float* bf2p,
                         const float* Ws1, const float* bs1,
                         float* ws, float* out){
  int b = blockIdx.x, t = threadIdx.x;
  __shared__ float ego_s[64], us_s[4][80], ctx_s[256], cego_s[256], hf_s[256];
  int ego = *ego_p;
  if (t < 64) ego_s[t] = ws[F_NF + ((size_t)b*NN+ego)*64 + t];
  for (int l=t; l<320; l+=256) us_s[l/80][l%80] = ws[F_US + (size_t)b*320 + l];
  __syncthreads();
  {  // ctx = (sum attn * edge_input) @ Wcv + bcv
    int h = t >> 6;
    const float* Wcv = ws + F_WCV;
    float a = ws[F_BCV + t];
    for (int i=0;i<64;i++) a += ego_s[i]*Wcv[(size_t)i*256+t];
    for (int i=0;i<16;i++) a += us_s[h][64+i]*Wcv[(size_t)(64+i)*256+t];
    for (int i=0;i<64;i++) a += us_s[h][i]*Wcv[(size_t)(80+i)*256+t];
    ctx_s[t]=a;
  }
  __syncthreads();
  {  // c_ego = ctx @ Wo + bo
    float a = bo[t];
    for (int i=0;i<256;i++) a += ctx_s[i]*Wo[(size_t)i*256+t];
    cego_s[t]=a; ws[F_CEGO + (size_t)b*256+t]=a;
  }
  __syncthreads();
  {  // hf = relu([ego, c_ego] @ Wf1 + bf1)
    float a = bf1p[t];
    for (int i=0;i<64;i++)  a += ego_s[i]*Wf1[(size_t)i*256+t];
    for (int i=0;i<256;i++) a += cego_s[i]*Wf1[(size_t)(64+i)*256+t];
    hf_s[t]=fmaxf(a,0.f);
  }
  __syncthreads();
  {  // h_ego_prime = hf @ Wf2 + bf2
    float a = bf2p[t];
    for (int i=0;i<256;i++) a += hf_s[i]*Wf2[(size_t)i*256+t];
    out[O_HEGO + (size_t)b*256+t] = a;
  }
  {  // cvec = c_ego @ Ws1[80:336] + bs1
    float a = bs1[t];
    for (int i=0;i<256;i++) a += cego_s[i]*Ws1[(size_t)(80+i)*256+t];
    ws[F_CVEC + (size_t)b*256+t]=a;
  }
}

// =============== edge score GEMM: score[b,e] = relu(F@Ws1[:80]+cvec)·w2col0 + bs2[0] ===============
__global__ __launch_bounds__(256) void k_bigscore(const int* ego_p, const float* Ws1,
                                                  const float* Ws2, const float* bs2, float* ws){
  int tile = blockIdx.x, b = blockIdx.y;
  int tid = threadIdx.x;
  __shared__ float Ft[80][64];          // F^T for 64 edges
  __shared__ float cv_s[256], w2_s[256];
  cv_s[tid] = ws[F_CVEC + (size_t)b*256 + tid];
  w2_s[tid] = Ws2[(size_t)tid*1537];            // Ws2[:,0]
  int ego = *ego_p;
  for (int l=tid; l<80*64; l+=256){
    int e = l/80, k = l - e*80;
    int eg = tile*64 + e;
    float v = 0.f;
    if (eg < EE){
      int node = eg<ego?eg:eg+1;
      v = (k<64) ? ws[F_NF + ((size_t)b*NN+node)*64 + k]
                 : ws[F_EF + ((size_t)b*EE+eg)*16 + (k-64)];
    }
    Ft[k][e] = v;
  }
  __syncthreads();
  int tc = tid & 31, te = tid >> 5;     // te: edge group (8 edges), tc: col group (8 cols)
  float acc[8][8];
  #pragma unroll
  for (int i=0;i<8;i++)
    #pragma unroll
    for (int j=0;j<8;j++) acc[i][j]=0.f;
  for (int k=0;k<80;k++){
    float4 a0 = *(const float4*)&Ft[k][te*8];
    float4 a1 = *(const float4*)&Ft[k][te*8+4];
    float av[8] = {a0.x,a0.y,a0.z,a0.w,a1.x,a1.y,a1.z,a1.w};
    float4 b0 = *(const float4*)(Ws1 + (size_t)k*256 + tc*8);
    float4 b1 = *(const float4*)(Ws1 + (size_t)k*256 + tc*8 + 4);
    float bv[8] = {b0.x,b0.y,b0.z,b0.w,b1.x,b1.y,b1.z,b1.w};
    #pragma unroll
    for (int i=0;i<8;i++)
      #pragma unroll
      for (int j=0;j<8;j++) acc[i][j] = fmaf(av[i], bv[j], acc[i][j]);
  }
  float bs20 = bs2[0];
  #pragma unroll
  for (int i=0;i<8;i++){
    float p = 0.f;
    #pragma unroll
    for (int j=0;j<8;j++){
      float hcol = acc[i][j] + cv_s[tc*8+j];
      p += fmaxf(hcol,0.f)*w2_s[tc*8+j];
    }
    #pragma unroll
    for (int m=16;m>0;m>>=1) p += __shfl_xor(p, m, 64);
    if (tc==0){
      int eg = tile*64 + te*8 + i;
      if (eg < EE) ws[F_SC2 + (size_t)b*EE + eg] = p + bs20;
    }
  }
}

// =============== top-5 (stable, ties -> lower index) + alpha softmax ===============
__global__ void k_topk(float* ws, float* out){
  int b = blockIdx.x, tid = threadIdx.x;
  __shared__ float sv[256]; __shared__ int si[256];
  __shared__ float tv[8];   __shared__ int tix[8];
  const float* s = ws + F_SC2 + (size_t)b*EE;
  float v0 = tid<EE ? s[tid] : -INFINITY;       int i0 = tid;
  float v1 = (tid+256)<EE ? s[tid+256] : -INFINITY; int i1 = tid+256;
  for (int t=0;t<5;t++){
    float bvv; int bii;
    if (v0 > v1 || (v0==v1 && i0<i1)){ bvv=v0; bii=i0; } else { bvv=v1; bii=i1; }
    sv[tid]=bvv; si[tid]=bii; __syncthreads();
    for (int st=128; st>0; st>>=1){
      if (tid<st){
        float ov=sv[tid+st]; int oi=si[tid+st];
        if (ov > sv[tid] || (ov==sv[tid] && oi<si[tid])){ sv[tid]=ov; si[tid]=oi; }
      }
      __syncthreads();
    }
    if (tid==0){ tv[t]=sv[0]; tix[t]=si[0]; }
    __syncthreads();
    int w = tix[t];
    if (i0==w) v0=-INFINITY;
    if (i1==w) v1=-INFINITY;
    __syncthreads();
  }
  if (tid==0){
    float m = tv[0];
    float ex[5]; float sum=0.f;
    for (int t=0;t<5;t++){ ex[t]=expf(tv[t]-m); sum+=ex[t]; }
    for (int t=0;t<5;t++){
      float al = ex[t]/sum;
      ws[F_ALPHA + (size_t)b*5+t] = al;
      ((int*)(ws + F_TKI))[b*5+t] = tix[t];
      out[O_TKI   + (size_t)b*5+t] = (float)tix[t];
      out[O_ALPHA + (size_t)b*5+t] = al;
    }
  }
}

// =============== selected hidden rows: hs[b,t,:] = relu(F_sel@Ws1[:80] + cvec) ===============
__global__ void k_hid(const int* ego_p, const float* Ws1, float* ws){
  int bt = blockIdx.x;               // b*5 + t
  int b = bt/5;
  int tid = threadIdx.x;
  __shared__ float fr[80];
  int e = ((const int*)(ws+F_TKI))[bt];
  int ego = *ego_p;
  int node = e<ego ? e : e+1;
  if (tid < 64)      fr[tid] = ws[F_NF + ((size_t)b*NN+node)*64 + tid];
  else if (tid < 80) fr[tid] = ws[F_EF + ((size_t)b*EE+e)*16 + (tid-64)];
  __syncthreads();
  float a = ws[F_CVEC + (size_t)b*256 + tid];
  for (int d=0;d<80;d++) a += fr[d]*Ws1[(size_t)d*256+tid];
  ws[F_HS + (size_t)bt*256 + tid] = fmaxf(a,0.f);
}

// =============== h_enc GEMM: out_sel[b,t,n] = (hs[b,t,:]·Ws2[:,1+n] + bs2[1+n])*alpha ===============
// grid (6, 128): r = 256-col chunk, g = pair of batches (10 rows). 1 col/thread, 10 acc.
// 768 blocks = 3/CU: TLP to hide L2 latency (round-4 k_enc at 192 blocks was latency-bound:
// occupancy 8.6%, VALUBusy 8%).
__global__ __launch_bounds__(256) void k_enc(const float* Ws2, const float* bs2,
                                             float* ws, float* out){
  int r = blockIdx.x, g = blockIdx.y, tid = threadIdx.x;
  int n = r*256 + tid;                 // 0..1535
  __shared__ float hs[10][256];
  __shared__ float al[10];
  int b0 = g*2;
  for (int l=tid; l<10*256; l+=256)
    hs[l>>8][l&255] = ws[F_HS + ((size_t)b0*5)*256 + l];
  if (tid<10) al[tid] = ws[F_ALPHA + (size_t)b0*5 + tid];
  __syncthreads();
  float acc[10];
  #pragma unroll
  for (int i=0;i<10;i++) acc[i]=0.f;
  const float* w2p = Ws2 + 1 + n;
  for (int j=0;j<256;j+=4){
    float w0 = w2p[(size_t)(j+0)*1537];
    float w1 = w2p[(size_t)(j+1)*1537];
    float w2 = w2p[(size_t)(j+2)*1537];
    float w3 = w2p[(size_t)(j+3)*1537];
    #pragma unroll
    for (int i=0;i<10;i++){
      float4 h = *(const float4*)&hs[i][j];
      acc[i] = fmaf(h.x,w0, fmaf(h.y,w1, fmaf(h.z,w2, fmaf(h.w,w3, acc[i]))));
    }
  }
  float bb = bs2[1+n];
  #pragma unroll
  for (int i=0;i<10;i++)
    out[O_SEL + ((size_t)(b0*5+i))*1536 + n] = (acc[i]+bb)*al[i];
}

extern "C" void kernel_launch(void* const* d_in, const int* in_sizes, int n_in,
                              void* d_out, int out_size, void* d_ws, size_t ws_size,
                              hipStream_t stream){
  const float* node_raw=(const float*)d_in[0];
  const float* edge_raw=(const float*)d_in[1];
  const int*  ego_p   =(const int*)d_in[2];
  const float* Wn =(const float*)d_in[3];  const float* bn =(const float*)d_in[4];
  const float* We =(const float*)d_in[5];  const float* be =(const float*)d_in[6];
  const float* Wq =(const float*)d_in[7];  const float* bq =(const float*)d_in[8];
  const float* Wkv=(const float*)d_in[9];  const float* bkv=(const float*)d_in[10];
  const float* Wiq=(const float*)d_in[11]; const float* biq=(const float*)d_in[12];
  const float* Wik=(const float*)d_in[13]; const float* bik=(const float*)d_in[14];
  const float* Wiv=(const float*)d_in[15]; const float* biv=(const float*)d_in[16];
  const float* Wo =(const float*)d_in[17]; const float* bo =(const float*)d_in[18];
  const float* Wf1=(const float*)d_in[19]; const float* bf1p=(const float*)d_in[20];
  const float* Wf2=(const float*)d_in[21]; const float* bf2p=(const float*)d_in[22];
  const float* Ws1=(const float*)d_in[23]; const float* bs1=(const float*)d_in[24];
  const float* Ws2=(const float*)d_in[25]; const float* bs2=(const float*)d_in[26];
  float* ws=(float*)d_ws;
  float* out=(float*)d_out;

  k_fuse<<<355,256,0,stream>>>(Wkv,bkv,Wik,bik,Wiv,biv,Wq,bq,Wiq,biq,ws);
  k_nf<<<(B*NN*64)/256,256,0,stream>>>(node_raw,Wn,bn,ws);
  k_ef<<<(B*EE*16)/256,256,0,stream>>>(edge_raw,We,be,ws);
  k_q<<<B,256,0,stream>>>(ego_p,ws);
  k_head<<<B*4,256,0,stream>>>(ego_p,ws);
  k_scores<<<B,256,0,stream>>>(ego_p,ws);
  k_softmax<<<B*4,256,0,stream>>>(ws);
  k_usum<<<B*4,128,0,stream>>>(ego_p,ws);
  k_bfinal<<<B,256,0,stream>>>(ego_p,Wo,bo,Wf1,bf1p,Wf2,bf2p,Ws1,bs1,ws,out);
  k_bigscore<<<dim3(8,B),256,0,stream>>>(ego_p,Ws1,Ws2,bs2,ws);
  k_topk<<<B,256,0,stream>>>(ws,out);
  k_hid<<<B*5,256,0,stream>>>(ego_p,Ws1,ws);
  k_enc<<<dim3(6,128),256,0,stream>>>(Ws2,bs2,ws,out);
}

// Round 7
// 289.550 us; speedup vs baseline: 1.3865x; 1.0072x over previous
//
#include <hip/hip_runtime.h>
#include <hip/hip_bf16.h>
#include <math.h>

constexpr int B = 256, NN = 512, EE = 511;

// ---- workspace layout (fp32 element offsets) ----
constexpr size_t F_NF    = 0;                               // node_feat  B*N*64
constexpr size_t F_EF    = F_NF   + (size_t)B*NN*64;        // edge_feat  B*E*16
constexpr size_t F_WCK   = F_EF   + (size_t)B*EE*16;        // fused K weight 144x256
constexpr size_t F_BCK   = F_WCK  + 144*256;
constexpr size_t F_WCV   = F_BCK  + 256;                    // fused V weight 144x256
constexpr size_t F_BCV   = F_WCV  + 144*256;
constexpr size_t F_WQ2   = F_BCV  + 256;                    // fused Q weight 64x256
constexpr size_t F_BQ2   = F_WQ2  + 64*256;
constexpr size_t F_Q     = F_BQ2  + 256;                    // q  B*256
constexpr size_t F_AW    = F_Q    + (size_t)B*256;          // per (b,h) score weights 80
constexpr size_t F_C0    = F_AW   + (size_t)B*4*80;         // per (b,h) score const
constexpr size_t F_SC    = F_C0   + (size_t)B*4;            // scores/attn B*4*E (dead after k_usum)
constexpr size_t F_US    = F_SC   + (size_t)B*4*EE;         // weighted sums B*4*80
constexpr size_t F_CEGO  = F_US   + (size_t)B*4*80;         // c_ego B*256
constexpr size_t F_CVEC  = F_CEGO + (size_t)B*256;          // cvec  B*256
constexpr size_t F_SC2   = F_CVEC + (size_t)B*256;          // edge scores B*E
constexpr size_t F_ALPHA = F_SC2  + (size_t)B*EE;           // B*5
constexpr size_t F_TKI   = F_ALPHA+ (size_t)B*5;            // B*5 (ints)
constexpr size_t F_HS    = F_SC;                            // selected hidden B*5*256 (aliases dead F_SC)

// ---- output layout (fp32 elements) ----
constexpr size_t O_HEGO  = 0;          // B*256
constexpr size_t O_SEL   = 65536;      // B*5*6*256
constexpr size_t O_TKI   = 2031616;    // B*5
constexpr size_t O_ALPHA = 2032896;    // B*5

// =============== weight fusion: Wck=WkvK@Wik, Wcv=WkvV@Wiv, Wq2=Wq@Wiq ===============
__global__ void k_fuse(const float* Wkv, const float* bkv, const float* Wik, const float* bik,
                       const float* Wiv, const float* biv, const float* Wq,  const float* bq,
                       const float* Wiq, const float* biq, float* ws){
  int t = blockIdx.x*256 + threadIdx.x;
  if (t < 36864){
    int r = t >> 8, c = t & 255;
    float a = 0.f;
    for (int m=0;m<256;m++) a += Wkv[(size_t)r*512+m] * Wik[(size_t)m*256+c];
    ws[F_WCK + t] = a;
  } else if (t < 37120){
    int c = t - 36864;
    float a = bik[c];
    for (int m=0;m<256;m++) a += bkv[m] * Wik[(size_t)m*256+c];
    ws[F_BCK + c] = a;
  } else if (t < 73984){
    int i = t - 37120; int r = i >> 8, c = i & 255;
    float a = 0.f;
    for (int m=0;m<256;m++) a += Wkv[(size_t)r*512+256+m] * Wiv[(size_t)m*256+c];
    ws[F_WCV + i] = a;
  } else if (t < 74240){
    int c = t - 73984;
    float a = biv[c];
    for (int m=0;m<256;m++) a += bkv[256+m] * Wiv[(size_t)m*256+c];
    ws[F_BCV + c] = a;
  } else if (t < 90624){
    int i = t - 74240; int r = i >> 8, c = i & 255;
    float a = 0.f;
    for (int m=0;m<256;m++) a += Wq[(size_t)r*256+m] * Wiq[(size_t)m*256+c];
    ws[F_WQ2 + i] = a;
  } else if (t < 90880){
    int c = t - 90624;
    float a = biq[c];
    for (int m=0;m<256;m++) a += bq[m] * Wiq[(size_t)m*256+c];
    ws[F_BQ2 + c] = a;
  }
}

// =============== node_feat = node_raw@Wn + bn ===============
__global__ void k_nf(const float* node_raw, const float* Wn, const float* bn, float* ws){
  size_t t = (size_t)blockIdx.x*256 + threadIdx.x;   // B*N*64 total
  int j = (int)(t & 63); size_t row = t >> 6;
  float a = bn[j];
  #pragma unroll
  for (int i=0;i<8;i++) a += node_raw[row*8+i] * Wn[(size_t)i*64+j];
  ws[F_NF + t] = a;
}

// =============== edge_feat = edge_raw@We + be ===============
__global__ void k_ef(const float* edge_raw, const float* We, const float* be, float* ws){
  size_t t = (size_t)blockIdx.x*256 + threadIdx.x;   // B*E*16 total
  int j = (int)(t & 15); size_t row = t >> 4;
  float a = be[j];
  #pragma unroll
  for (int i=0;i<3;i++) a += edge_raw[row*3+i] * We[(size_t)i*16+j];
  ws[F_EF + t] = a;
}

// =============== q[b] = ego@Wq2 + bq2 ===============
__global__ void k_q(const int* ego_p, float* ws){
  int b = blockIdx.x, c = threadIdx.x;
  int ego = *ego_p;
  const float* egf = ws + F_NF + ((size_t)b*NN + ego)*64;
  const float* Wq2 = ws + F_WQ2;
  float a = ws[F_BQ2 + c];
  for (int i=0;i<64;i++) a += egf[i]*Wq2[(size_t)i*256+c];
  ws[F_Q + (size_t)b*256 + c] = a;
}

// =============== per (b,h): aw (80) and c0 so score = (c0 + F·aw)/8 ===============
__global__ void k_head(const int* ego_p, float* ws){
  int b = blockIdx.x >> 2, h = blockIdx.x & 3;
  int tid = threadIdx.x;
  __shared__ float qh[64];
  __shared__ float red[256];
  if (tid < 64) qh[tid] = ws[F_Q + (size_t)b*256 + h*64 + tid];
  __syncthreads();
  const float* Wck = ws + F_WCK;
  float p = 0.f;
  size_t awbase = F_AW + ((size_t)(b*4+h))*80;
  if (tid < 64){                               // neighbor-part weights (ei rows 80..143)
    const float* wr = Wck + (size_t)(80+tid)*256 + h*64;
    float a=0.f; for(int d=0;d<64;d++) a += wr[d]*qh[d];
    ws[awbase + tid] = a;
  } else if (tid < 80){                        // edge-part weights (rows 64..79)
    int i = tid-64;
    const float* wr = Wck + (size_t)(64+i)*256 + h*64;
    float a=0.f; for(int d=0;d<64;d++) a += wr[d]*qh[d];
    ws[awbase + 64 + i] = a;
  } else if (tid < 144){                       // ego-part constant (rows 0..63)
    int j = tid-80;
    const float* wr = Wck + (size_t)j*256 + h*64;
    float a=0.f; for(int d=0;d<64;d++) a += wr[d]*qh[d];
    int ego = *ego_p;
    p = ws[F_NF + ((size_t)b*NN+ego)*64 + j] * a;
  } else if (tid < 208){                       // bias constant
    int d = tid-144;
    p = ws[F_BCK + h*64 + d] * qh[d];
  }
  red[tid]=p; __syncthreads();
  for (int s=128;s>0;s>>=1){ if(tid<s) red[tid]+=red[tid+s]; __syncthreads(); }
  if (tid==0) ws[F_C0 + b*4 + h] = red[0];
}

// =============== attention scores for all heads ===============
__global__ void k_scores(const int* ego_p, float* ws){
  int b = blockIdx.x, tid = threadIdx.x;
  __shared__ float awz[4][80];
  __shared__ float c0s[4];
  for (int l=tid; l<320; l+=256) awz[l/80][l%80] = ws[F_AW + (size_t)b*320 + l];
  if (tid<4) c0s[tid] = ws[F_C0 + b*4 + tid];
  __syncthreads();
  int ego = *ego_p;
  for (int e=tid; e<EE; e+=256){
    int node = e < ego ? e : e+1;
    const float4* nr = (const float4*)(ws + F_NF + ((size_t)b*NN+node)*64);
    const float4* er = (const float4*)(ws + F_EF + ((size_t)b*EE+e)*16);
    float s[4] = {c0s[0],c0s[1],c0s[2],c0s[3]};
    #pragma unroll
    for (int i=0;i<16;i++){
      float4 x = nr[i];
      #pragma unroll
      for (int h=0;h<4;h++)
        s[h] += x.x*awz[h][i*4] + x.y*awz[h][i*4+1] + x.z*awz[h][i*4+2] + x.w*awz[h][i*4+3];
    }
    #pragma unroll
    for (int i=0;i<4;i++){
      float4 x = er[i];
      #pragma unroll
      for (int h=0;h<4;h++)
        s[h] += x.x*awz[h][64+i*4] + x.y*awz[h][64+i*4+1] + x.z*awz[h][64+i*4+2] + x.w*awz[h][64+i*4+3];
    }
    #pragma unroll
    for (int h=0;h<4;h++) ws[F_SC + ((size_t)(b*4+h))*EE + e] = s[h]*0.125f;
  }
}

// =============== softmax over E per (b,h), in place ===============
__global__ void k_softmax(float* ws){
  int bh = blockIdx.x, tid = threadIdx.x;
  float* s = ws + F_SC + (size_t)bh*EE;
  __shared__ float red[256];
  float v0 = tid<EE ? s[tid] : -INFINITY;
  float v1 = tid+256<EE ? s[tid+256] : -INFINITY;
  red[tid] = fmaxf(v0,v1); __syncthreads();
  for (int st=128;st>0;st>>=1){ if(tid<st) red[tid]=fmaxf(red[tid],red[tid+st]); __syncthreads(); }
  float m = red[0]; __syncthreads();
  float e0 = tid<EE ? expf(v0-m) : 0.f;
  float e1 = tid+256<EE ? expf(v1-m) : 0.f;
  red[tid] = e0+e1; __syncthreads();
  for (int st=128;st>0;st>>=1){ if(tid<st) red[tid]+=red[tid+st]; __syncthreads(); }
  float inv = 1.f/red[0];
  if (tid<EE) s[tid] = e0*inv;
  if (tid+256<EE) s[tid+256] = e1*inv;
}

// =============== u[b,h,d] = sum_e attn * F[b,e,d]  (d<64: nbr, d>=64: ef) ===============
__global__ void k_usum(const int* ego_p, float* ws){
  int b = blockIdx.x>>2, h = blockIdx.x&3, d = threadIdx.x;
  if (d >= 80) return;
  const float* at = ws + F_SC + ((size_t)(b*4+h))*EE;
  int ego = *ego_p;
  float a = 0.f;
  if (d < 64){
    const float* base = ws + F_NF + (size_t)b*NN*64 + d;
    for (int e=0;e<EE;e++){
      int node = e<ego?e:e+1;
      a += at[e]*base[(size_t)node*64];
    }
  } else {
    const float* base = ws + F_EF + (size_t)b*EE*16 + (d-64);
    for (int e=0;e<EE;e++) a += at[e]*base[(size_t)e*16];
  }
  ws[F_US + ((size_t)(b*4+h))*80 + d] = a;
}

// =============== per-b tail: ctx -> c_ego -> h_ego_prime(out) + cvec ===============
__global__ void k_bfinal(const int* ego_p,
                         const float* Wo, const float* bo,
                         const float* Wf1, const float* bf1p,
                         const float* Wf2, const float* bf2p,
                         const float* Ws1, const float* bs1,
                         float* ws, float* out){
  int b = blockIdx.x, t = threadIdx.x;
  __shared__ float ego_s[64], us_s[4][80], ctx_s[256], cego_s[256], hf_s[256];
  int ego = *ego_p;
  if (t < 64) ego_s[t] = ws[F_NF + ((size_t)b*NN+ego)*64 + t];
  for (int l=t; l<320; l+=256) us_s[l/80][l%80] = ws[F_US + (size_t)b*320 + l];
  __syncthreads();
  {  // ctx = (sum attn * edge_input) @ Wcv + bcv
    int h = t >> 6;
    const float* Wcv = ws + F_WCV;
    float a = ws[F_BCV + t];
    for (int i=0;i<64;i++) a += ego_s[i]*Wcv[(size_t)i*256+t];
    for (int i=0;i<16;i++) a += us_s[h][64+i]*Wcv[(size_t)(64+i)*256+t];
    for (int i=0;i<64;i++) a += us_s[h][i]*Wcv[(size_t)(80+i)*256+t];
    ctx_s[t]=a;
  }
  __syncthreads();
  {  // c_ego = ctx @ Wo + bo
    float a = bo[t];
    for (int i=0;i<256;i++) a += ctx_s[i]*Wo[(size_t)i*256+t];
    cego_s[t]=a; ws[F_CEGO + (size_t)b*256+t]=a;
  }
  __syncthreads();
  {  // hf = relu([ego, c_ego] @ Wf1 + bf1)
    float a = bf1p[t];
    for (int i=0;i<64;i++)  a += ego_s[i]*Wf1[(size_t)i*256+t];
    for (int i=0;i<256;i++) a += cego_s[i]*Wf1[(size_t)(64+i)*256+t];
    hf_s[t]=fmaxf(a,0.f);
  }
  __syncthreads();
  {  // h_ego_prime = hf @ Wf2 + bf2
    float a = bf2p[t];
    for (int i=0;i<256;i++) a += hf_s[i]*Wf2[(size_t)i*256+t];
    out[O_HEGO + (size_t)b*256+t] = a;
  }
  {  // cvec = c_ego @ Ws1[80:336] + bs1
    float a = bs1[t];
    for (int i=0;i<256;i++) a += cego_s[i]*Ws1[(size_t)(80+i)*256+t];
    ws[F_CVEC + (size_t)b*256+t]=a;
  }
}

// =============== edge score GEMM: score[b,e] = relu(F@Ws1[:80]+cvec)·w2col0 + bs2[0] ===============
// LDS tile stored UN-transposed Fe[e][k]: staging writes step +1 float per lane
// (conflict-free; the old Ft[k][e] layout stepped 256B/lane = 32-way conflict,
// SQ_LDS_BANK_CONFLICT 9.4M). A-operand reads are wave-broadcast scalars (free).
__global__ __launch_bounds__(256) void k_bigscore(const int* ego_p, const float* Ws1,
                                                  const float* Ws2, const float* bs2, float* ws){
  int tile = blockIdx.x, b = blockIdx.y;
  int tid = threadIdx.x;
  __shared__ float Fe[64][80];          // F for 64 edges, [edge][k]
  __shared__ float cv_s[256], w2_s[256];
  cv_s[tid] = ws[F_CVEC + (size_t)b*256 + tid];
  w2_s[tid] = Ws2[(size_t)tid*1537];            // Ws2[:,0]
  int ego = *ego_p;
  for (int l=tid; l<80*64; l+=256){
    int e = l/80, k = l - e*80;        // consecutive lanes -> consecutive k: coalesced global
    int eg = tile*64 + e;
    float v = 0.f;
    if (eg < EE){
      int node = eg<ego?eg:eg+1;
      v = (k<64) ? ws[F_NF + ((size_t)b*NN+node)*64 + k]
                 : ws[F_EF + ((size_t)b*EE+eg)*16 + (k-64)];
    }
    Fe[e][k] = v;                      // conflict-free LDS write
  }
  __syncthreads();
  int tc = tid & 31, te = tid >> 5;     // te: edge group (8 edges), tc: col group (8 cols)
  float acc[8][8];
  #pragma unroll
  for (int i=0;i<8;i++)
    #pragma unroll
    for (int j=0;j<8;j++) acc[i][j]=0.f;
  for (int k=0;k<80;k++){
    float av[8];
    #pragma unroll
    for (int i=0;i<8;i++) av[i] = Fe[te*8+i][k];   // broadcast read (lanes share addr)
    float4 b0 = *(const float4*)(Ws1 + (size_t)k*256 + tc*8);
    float4 b1 = *(const float4*)(Ws1 + (size_t)k*256 + tc*8 + 4);
    float bv[8] = {b0.x,b0.y,b0.z,b0.w,b1.x,b1.y,b1.z,b1.w};
    #pragma unroll
    for (int i=0;i<8;i++)
      #pragma unroll
      for (int j=0;j<8;j++) acc[i][j] = fmaf(av[i], bv[j], acc[i][j]);
  }
  float bs20 = bs2[0];
  #pragma unroll
  for (int i=0;i<8;i++){
    float p = 0.f;
    #pragma unroll
    for (int j=0;j<8;j++){
      float hcol = acc[i][j] + cv_s[tc*8+j];
      p += fmaxf(hcol,0.f)*w2_s[tc*8+j];
    }
    #pragma unroll
    for (int m=16;m>0;m>>=1) p += __shfl_xor(p, m, 64);
    if (tc==0){
      int eg = tile*64 + te*8 + i;
      if (eg < EE) ws[F_SC2 + (size_t)b*EE + eg] = p + bs20;
    }
  }
}

// =============== top-5 (stable, ties -> lower index) + alpha softmax ===============
__global__ void k_topk(float* ws, float* out){
  int b = blockIdx.x, tid = threadIdx.x;
  __shared__ float sv[256]; __shared__ int si[256];
  __shared__ float tv[8];   __shared__ int tix[8];
  const float* s = ws + F_SC2 + (size_t)b*EE;
  float v0 = tid<EE ? s[tid] : -INFINITY;       int i0 = tid;
  float v1 = (tid+256)<EE ? s[tid+256] : -INFINITY; int i1 = tid+256;
  for (int t=0;t<5;t++){
    float bvv; int bii;
    if (v0 > v1 || (v0==v1 && i0<i1)){ bvv=v0; bii=i0; } else { bvv=v1; bii=i1; }
    sv[tid]=bvv; si[tid]=bii; __syncthreads();
    for (int st=128; st>0; st>>=1){
      if (tid<st){
        float ov=sv[tid+st]; int oi=si[tid+st];
        if (ov > sv[tid] || (ov==sv[tid] && oi<si[tid])){ sv[tid]=ov; si[tid]=oi; }
      }
      __syncthreads();
    }
    if (tid==0){ tv[t]=sv[0]; tix[t]=si[0]; }
    __syncthreads();
    int w = tix[t];
    if (i0==w) v0=-INFINITY;
    if (i1==w) v1=-INFINITY;
    __syncthreads();
  }
  if (tid==0){
    float m = tv[0];
    float ex[5]; float sum=0.f;
    for (int t=0;t<5;t++){ ex[t]=expf(tv[t]-m); sum+=ex[t]; }
    for (int t=0;t<5;t++){
      float al = ex[t]/sum;
      ws[F_ALPHA + (size_t)b*5+t] = al;
      ((int*)(ws + F_TKI))[b*5+t] = tix[t];
      out[O_TKI   + (size_t)b*5+t] = (float)tix[t];
      out[O_ALPHA + (size_t)b*5+t] = al;
    }
  }
}

// =============== selected hidden rows: hs[b,t,:] = relu(F_sel@Ws1[:80] + cvec) ===============
__global__ void k_hid(const int* ego_p, const float* Ws1, float* ws){
  int bt = blockIdx.x;               // b*5 + t
  int b = bt/5;
  int tid = threadIdx.x;
  __shared__ float fr[80];
  int e = ((const int*)(ws+F_TKI))[bt];
  int ego = *ego_p;
  int node = e<ego ? e : e+1;
  if (tid < 64)      fr[tid] = ws[F_NF + ((size_t)b*NN+node)*64 + tid];
  else if (tid < 80) fr[tid] = ws[F_EF + ((size_t)b*EE+e)*16 + (tid-64)];
  __syncthreads();
  float a = ws[F_CVEC + (size_t)b*256 + tid];
  for (int d=0;d<80;d++) a += fr[d]*Ws1[(size_t)d*256+tid];
  ws[F_HS + (size_t)bt*256 + tid] = fmaxf(a,0.f);
}

// =============== h_enc GEMM: out_sel[b,t,n] = (hs[b,t,:]·Ws2[:,1+n] + bs2[1+n])*alpha ===============
// grid (6, 128): r = 256-col chunk, g = pair of batches (10 rows). 1 col/thread, 10 acc.
// 768 blocks = 3/CU: TLP to hide L2 latency (round-4 k_enc at 192 blocks was latency-bound).
__global__ __launch_bounds__(256) void k_enc(const float* Ws2, const float* bs2,
                                             float* ws, float* out){
  int r = blockIdx.x, g = blockIdx.y, tid = threadIdx.x;
  int n = r*256 + tid;                 // 0..1535
  __shared__ float hs[10][256];
  __shared__ float al[10];
  int b0 = g*2;
  for (int l=tid; l<10*256; l+=256)
    hs[l>>8][l&255] = ws[F_HS + ((size_t)b0*5)*256 + l];
  if (tid<10) al[tid] = ws[F_ALPHA + (size_t)b0*5 + tid];
  __syncthreads();
  float acc[10];
  #pragma unroll
  for (int i=0;i<10;i++) acc[i]=0.f;
  const float* w2p = Ws2 + 1 + n;
  for (int j=0;j<256;j+=4){
    float w0 = w2p[(size_t)(j+0)*1537];
    float w1 = w2p[(size_t)(j+1)*1537];
    float w2 = w2p[(size_t)(j+2)*1537];
    float w3 = w2p[(size_t)(j+3)*1537];
    #pragma unroll
    for (int i=0;i<10;i++){
      float4 h = *(const float4*)&hs[i][j];
      acc[i] = fmaf(h.x,w0, fmaf(h.y,w1, fmaf(h.z,w2, fmaf(h.w,w3, acc[i]))));
    }
  }
  float bb = bs2[1+n];
  #pragma unroll
  for (int i=0;i<10;i++)
    out[O_SEL + ((size_t)(b0*5+i))*1536 + n] = (acc[i]+bb)*al[i];
}

extern "C" void kernel_launch(void* const* d_in, const int* in_sizes, int n_in,
                              void* d_out, int out_size, void* d_ws, size_t ws_size,
                              hipStream_t stream){
  const float* node_raw=(const float*)d_in[0];
  const float* edge_raw=(const float*)d_in[1];
  const int*  ego_p   =(const int*)d_in[2];
  const float* Wn =(const float*)d_in[3];  const float* bn =(const float*)d_in[4];
  const float* We =(const float*)d_in[5];  const float* be =(const float*)d_in[6];
  const float* Wq =(const float*)d_in[7];  const float* bq =(const float*)d_in[8];
  const float* Wkv=(const float*)d_in[9];  const float* bkv=(const float*)d_in[10];
  const float* Wiq=(const float*)d_in[11]; const float* biq=(const float*)d_in[12];
  const float* Wik=(const float*)d_in[13]; const float* bik=(const float*)d_in[14];
  const float* Wiv=(const float*)d_in[15]; const float* biv=(const float*)d_in[16];
  const float* Wo =(const float*)d_in[17]; const float* bo =(const float*)d_in[18];
  const float* Wf1=(const float*)d_in[19]; const float* bf1p=(const float*)d_in[20];
  const float* Wf2=(const float*)d_in[21]; const float* bf2p=(const float*)d_in[22];
  const float* Ws1=(const float*)d_in[23]; const float* bs1=(const float*)d_in[24];
  const float* Ws2=(const float*)d_in[25]; const float* bs2=(const float*)d_in[26];
  float* ws=(float*)d_ws;
  float* out=(float*)d_out;

  k_fuse<<<355,256,0,stream>>>(Wkv,bkv,Wik,bik,Wiv,biv,Wq,bq,Wiq,biq,ws);
  k_nf<<<(B*NN*64)/256,256,0,stream>>>(node_raw,Wn,bn,ws);
  k_ef<<<(B*EE*16)/256,256,0,stream>>>(edge_raw,We,be,ws);
  k_q<<<B,256,0,stream>>>(ego_p,ws);
  k_head<<<B*4,256,0,stream>>>(ego_p,ws);
  k_scores<<<B,256,0,stream>>>(ego_p,ws);
  k_softmax<<<B*4,256,0,stream>>>(ws);
  k_usum<<<B*4,128,0,stream>>>(ego_p,ws);
  k_bfinal<<<B,256,0,stream>>>(ego_p,Wo,bo,Wf1,bf1p,Wf2,bf2p,Ws1,bs1,ws,out);
  k_bigscore<<<dim3(8,B),256,0,stream>>>(ego_p,Ws1,Ws2,bs2,ws);
  k_topk<<<B,256,0,stream>>>(ws,out);
  k_hid<<<B*5,256,0,stream>>>(ego_p,Ws1,ws);
  k_enc<<<dim3(6,128),256,0,stream>>>(Ws2,bs2,ws,out);
}

// Round 8
// 287.720 us; speedup vs baseline: 1.3953x; 1.0064x over previous
//
#include <hip/hip_runtime.h>
#include <hip/hip_bf16.h>
#include <math.h>

constexpr int B = 256, NN = 512, EE = 511;

// ---- workspace layout (fp32 element offsets) ----
constexpr size_t F_NF    = 0;                               // node_feat  B*N*64
constexpr size_t F_EF    = F_NF   + (size_t)B*NN*64;        // edge_feat  B*E*16
constexpr size_t F_WCK   = F_EF   + (size_t)B*EE*16;        // fused K weight 144x256
constexpr size_t F_BCK   = F_WCK  + 144*256;
constexpr size_t F_WCV   = F_BCK  + 256;                    // fused V weight 144x256
constexpr size_t F_BCV   = F_WCV  + 144*256;
constexpr size_t F_WQ2   = F_BCV  + 256;                    // fused Q weight 64x256
constexpr size_t F_BQ2   = F_WQ2  + 64*256;
constexpr size_t F_Q     = F_BQ2  + 256;                    // q  B*256
constexpr size_t F_AW    = F_Q    + (size_t)B*256;          // per (b,h) score weights 80
constexpr size_t F_C0    = F_AW   + (size_t)B*4*80;         // per (b,h) score const
constexpr size_t F_SC    = F_C0   + (size_t)B*4;            // scores/attn B*4*E (dead after k_usum)
constexpr size_t F_US    = F_SC   + (size_t)B*4*EE;         // weighted sums B*4*80
constexpr size_t F_CEGO  = F_US   + (size_t)B*4*80;         // c_ego B*256
constexpr size_t F_CVEC  = F_CEGO + (size_t)B*256;          // cvec  B*256
constexpr size_t F_SC2   = F_CVEC + (size_t)B*256;          // edge scores B*E
constexpr size_t F_ALPHA = F_SC2  + (size_t)B*EE;           // B*5
constexpr size_t F_TKI   = F_ALPHA+ (size_t)B*5;            // B*5 (ints)
constexpr size_t F_HS    = F_SC;                            // selected hidden B*5*256 (aliases dead F_SC)

// ---- output layout (fp32 elements) ----
constexpr size_t O_HEGO  = 0;          // B*256
constexpr size_t O_SEL   = 65536;      // B*5*6*256
constexpr size_t O_TKI   = 2031616;    // B*5
constexpr size_t O_ALPHA = 2032896;    // B*5

// =============== weight fusion: Wck=WkvK@Wik, Wcv=WkvV@Wiv, Wq2=Wq@Wiq ===============
__global__ void k_fuse(const float* Wkv, const float* bkv, const float* Wik, const float* bik,
                       const float* Wiv, const float* biv, const float* Wq,  const float* bq,
                       const float* Wiq, const float* biq, float* ws){
  int t = blockIdx.x*256 + threadIdx.x;
  if (t < 36864){
    int r = t >> 8, c = t & 255;
    float a = 0.f;
    for (int m=0;m<256;m++) a += Wkv[(size_t)r*512+m] * Wik[(size_t)m*256+c];
    ws[F_WCK + t] = a;
  } else if (t < 37120){
    int c = t - 36864;
    float a = bik[c];
    for (int m=0;m<256;m++) a += bkv[m] * Wik[(size_t)m*256+c];
    ws[F_BCK + c] = a;
  } else if (t < 73984){
    int i = t - 37120; int r = i >> 8, c = i & 255;
    float a = 0.f;
    for (int m=0;m<256;m++) a += Wkv[(size_t)r*512+256+m] * Wiv[(size_t)m*256+c];
    ws[F_WCV + i] = a;
  } else if (t < 74240){
    int c = t - 73984;
    float a = biv[c];
    for (int m=0;m<256;m++) a += bkv[256+m] * Wiv[(size_t)m*256+c];
    ws[F_BCV + c] = a;
  } else if (t < 90624){
    int i = t - 74240; int r = i >> 8, c = i & 255;
    float a = 0.f;
    for (int m=0;m<256;m++) a += Wq[(size_t)r*256+m] * Wiq[(size_t)m*256+c];
    ws[F_WQ2 + i] = a;
  } else if (t < 90880){
    int c = t - 90624;
    float a = biq[c];
    for (int m=0;m<256;m++) a += bq[m] * Wiq[(size_t)m*256+c];
    ws[F_BQ2 + c] = a;
  }
}

// =============== node_feat = node_raw@Wn + bn ===============
__global__ void k_nf(const float* node_raw, const float* Wn, const float* bn, float* ws){
  size_t t = (size_t)blockIdx.x*256 + threadIdx.x;   // B*N*64 total
  int j = (int)(t & 63); size_t row = t >> 6;
  float a = bn[j];
  #pragma unroll
  for (int i=0;i<8;i++) a += node_raw[row*8+i] * Wn[(size_t)i*64+j];
  ws[F_NF + t] = a;
}

// =============== edge_feat = edge_raw@We + be ===============
__global__ void k_ef(const float* edge_raw, const float* We, const float* be, float* ws){
  size_t t = (size_t)blockIdx.x*256 + threadIdx.x;   // B*E*16 total
  int j = (int)(t & 15); size_t row = t >> 4;
  float a = be[j];
  #pragma unroll
  for (int i=0;i<3;i++) a += edge_raw[row*3+i] * We[(size_t)i*16+j];
  ws[F_EF + t] = a;
}

// =============== q[b] = ego@Wq2 + bq2 ===============
__global__ void k_q(const int* ego_p, float* ws){
  int b = blockIdx.x, c = threadIdx.x;
  int ego = *ego_p;
  const float* egf = ws + F_NF + ((size_t)b*NN + ego)*64;
  const float* Wq2 = ws + F_WQ2;
  float a = ws[F_BQ2 + c];
  for (int i=0;i<64;i++) a += egf[i]*Wq2[(size_t)i*256+c];
  ws[F_Q + (size_t)b*256 + c] = a;
}

// =============== per (b,h): aw (80) and c0 so score = (c0 + F·aw)/8 ===============
__global__ void k_head(const int* ego_p, float* ws){
  int b = blockIdx.x >> 2, h = blockIdx.x & 3;
  int tid = threadIdx.x;
  __shared__ float qh[64];
  __shared__ float red[256];
  if (tid < 64) qh[tid] = ws[F_Q + (size_t)b*256 + h*64 + tid];
  __syncthreads();
  const float* Wck = ws + F_WCK;
  float p = 0.f;
  size_t awbase = F_AW + ((size_t)(b*4+h))*80;
  if (tid < 64){                               // neighbor-part weights (ei rows 80..143)
    const float* wr = Wck + (size_t)(80+tid)*256 + h*64;
    float a=0.f; for(int d=0;d<64;d++) a += wr[d]*qh[d];
    ws[awbase + tid] = a;
  } else if (tid < 80){                        // edge-part weights (rows 64..79)
    int i = tid-64;
    const float* wr = Wck + (size_t)(64+i)*256 + h*64;
    float a=0.f; for(int d=0;d<64;d++) a += wr[d]*qh[d];
    ws[awbase + 64 + i] = a;
  } else if (tid < 144){                       // ego-part constant (rows 0..63)
    int j = tid-80;
    const float* wr = Wck + (size_t)j*256 + h*64;
    float a=0.f; for(int d=0;d<64;d++) a += wr[d]*qh[d];
    int ego = *ego_p;
    p = ws[F_NF + ((size_t)b*NN+ego)*64 + j] * a;
  } else if (tid < 208){                       // bias constant
    int d = tid-144;
    p = ws[F_BCK + h*64 + d] * qh[d];
  }
  red[tid]=p; __syncthreads();
  for (int s=128;s>0;s>>=1){ if(tid<s) red[tid]+=red[tid+s]; __syncthreads(); }
  if (tid==0) ws[F_C0 + b*4 + h] = red[0];
}

// =============== attention scores for all heads ===============
__global__ void k_scores(const int* ego_p, float* ws){
  int b = blockIdx.x, tid = threadIdx.x;
  __shared__ float awz[4][80];
  __shared__ float c0s[4];
  for (int l=tid; l<320; l+=256) awz[l/80][l%80] = ws[F_AW + (size_t)b*320 + l];
  if (tid<4) c0s[tid] = ws[F_C0 + b*4 + tid];
  __syncthreads();
  int ego = *ego_p;
  for (int e=tid; e<EE; e+=256){
    int node = e < ego ? e : e+1;
    const float4* nr = (const float4*)(ws + F_NF + ((size_t)b*NN+node)*64);
    const float4* er = (const float4*)(ws + F_EF + ((size_t)b*EE+e)*16);
    float s[4] = {c0s[0],c0s[1],c0s[2],c0s[3]};
    #pragma unroll
    for (int i=0;i<16;i++){
      float4 x = nr[i];
      #pragma unroll
      for (int h=0;h<4;h++)
        s[h] += x.x*awz[h][i*4] + x.y*awz[h][i*4+1] + x.z*awz[h][i*4+2] + x.w*awz[h][i*4+3];
    }
    #pragma unroll
    for (int i=0;i<4;i++){
      float4 x = er[i];
      #pragma unroll
      for (int h=0;h<4;h++)
        s[h] += x.x*awz[h][64+i*4] + x.y*awz[h][64+i*4+1] + x.z*awz[h][64+i*4+2] + x.w*awz[h][64+i*4+3];
    }
    #pragma unroll
    for (int h=0;h<4;h++) ws[F_SC + ((size_t)(b*4+h))*EE + e] = s[h]*0.125f;
  }
}

// =============== softmax over E per (b,h), in place ===============
__global__ void k_softmax(float* ws){
  int bh = blockIdx.x, tid = threadIdx.x;
  float* s = ws + F_SC + (size_t)bh*EE;
  __shared__ float red[256];
  float v0 = tid<EE ? s[tid] : -INFINITY;
  float v1 = tid+256<EE ? s[tid+256] : -INFINITY;
  red[tid] = fmaxf(v0,v1); __syncthreads();
  for (int st=128;st>0;st>>=1){ if(tid<st) red[tid]=fmaxf(red[tid],red[tid+st]); __syncthreads(); }
  float m = red[0]; __syncthreads();
  float e0 = tid<EE ? expf(v0-m) : 0.f;
  float e1 = tid+256<EE ? expf(v1-m) : 0.f;
  red[tid] = e0+e1; __syncthreads();
  for (int st=128;st>0;st>>=1){ if(tid<st) red[tid]+=red[tid+st]; __syncthreads(); }
  float inv = 1.f/red[0];
  if (tid<EE) s[tid] = e0*inv;
  if (tid+256<EE) s[tid+256] = e1*inv;
}

// =============== u[b,h,d] = sum_e attn * F[b,e,d]  (d<64: nbr, d>=64: ef) ===============
__global__ void k_usum(const int* ego_p, float* ws){
  int b = blockIdx.x>>2, h = blockIdx.x&3, d = threadIdx.x;
  if (d >= 80) return;
  const float* at = ws + F_SC + ((size_t)(b*4+h))*EE;
  int ego = *ego_p;
  float a = 0.f;
  if (d < 64){
    const float* base = ws + F_NF + (size_t)b*NN*64 + d;
    for (int e=0;e<EE;e++){
      int node = e<ego?e:e+1;
      a += at[e]*base[(size_t)node*64];
    }
  } else {
    const float* base = ws + F_EF + (size_t)b*EE*16 + (d-64);
    for (int e=0;e<EE;e++) a += at[e]*base[(size_t)e*16];
  }
  ws[F_US + ((size_t)(b*4+h))*80 + d] = a;
}

// =============== per-b tail: ctx -> c_ego -> h_ego_prime(out) + cvec ===============
__global__ void k_bfinal(const int* ego_p,
                         const float* Wo, const float* bo,
                         const float* Wf1, const float* bf1p,
                         const float* Wf2, const float* bf2p,
                         const float* Ws1, const float* bs1,
                         float* ws, float* out){
  int b = blockIdx.x, t = threadIdx.x;
  __shared__ float ego_s[64], us_s[4][80], ctx_s[256], cego_s[256], hf_s[256];
  int ego = *ego_p;
  if (t < 64) ego_s[t] = ws[F_NF + ((size_t)b*NN+ego)*64 + t];
  for (int l=t; l<320; l+=256) us_s[l/80][l%80] = ws[F_US + (size_t)b*320 + l];
  __syncthreads();
  {  // ctx = (sum attn * edge_input) @ Wcv + bcv
    int h = t >> 6;
    const float* Wcv = ws + F_WCV;
    float a = ws[F_BCV + t];
    for (int i=0;i<64;i++) a += ego_s[i]*Wcv[(size_t)i*256+t];
    for (int i=0;i<16;i++) a += us_s[h][64+i]*Wcv[(size_t)(64+i)*256+t];
    for (int i=0;i<64;i++) a += us_s[h][i]*Wcv[(size_t)(80+i)*256+t];
    ctx_s[t]=a;
  }
  __syncthreads();
  {  // c_ego = ctx @ Wo + bo
    float a = bo[t];
    for (int i=0;i<256;i++) a += ctx_s[i]*Wo[(size_t)i*256+t];
    cego_s[t]=a; ws[F_CEGO + (size_t)b*256+t]=a;
  }
  __syncthreads();
  {  // hf = relu([ego, c_ego] @ Wf1 + bf1)
    float a = bf1p[t];
    for (int i=0;i<64;i++)  a += ego_s[i]*Wf1[(size_t)i*256+t];
    for (int i=0;i<256;i++) a += cego_s[i]*Wf1[(size_t)(64+i)*256+t];
    hf_s[t]=fmaxf(a,0.f);
  }
  __syncthreads();
  {  // h_ego_prime = hf @ Wf2 + bf2
    float a = bf2p[t];
    for (int i=0;i<256;i++) a += hf_s[i]*Wf2[(size_t)i*256+t];
    out[O_HEGO + (size_t)b*256+t] = a;
  }
  {  // cvec = c_ego @ Ws1[80:336] + bs1
    float a = bs1[t];
    for (int i=0;i<256;i++) a += cego_s[i]*Ws1[(size_t)(80+i)*256+t];
    ws[F_CVEC + (size_t)b*256+t]=a;
  }
}

// =============== edge score GEMM: score[b,e] = relu(F@Ws1[:80]+cvec)·w2col0 + bs2[0] ===============
// v3: 512 threads, per-thread 4 edges x 8 cols (acc[4][8]=32 VGPR - fits registers; the
// round-6/7 acc[8][8] version compiled to VGPR=48 => compiler split/spilled the k-loop).
// Ws1 staged in 16-row LDS chunks: read once per block from L2. A-reads: aligned ds_read_b128.
__global__ __launch_bounds__(512) void k_bigscore(const int* ego_p, const float* Ws1,
                                                  const float* Ws2, const float* bs2, float* ws){
  int tile = blockIdx.x, b = blockIdx.y;
  int tid = threadIdx.x;
  __shared__ float Fe[64][80];          // 20 KB, [edge][k], row stride 320B (16B-aligned)
  __shared__ float Bs[16][256];         // 16 KB, k-chunk of Ws1
  __shared__ float cv_s[256], w2_s[256];
  int ego = *ego_p;
  if (tid < 256){
    cv_s[tid] = ws[F_CVEC + (size_t)b*256 + tid];
    w2_s[tid] = Ws2[(size_t)tid*1537];          // Ws2[:,0]
  }
  for (int l=tid; l<80*64; l+=512){
    int e = l/80, k = l - e*80;        // consecutive lanes -> consecutive k: coalesced + conflict-free
    int eg = tile*64 + e;
    float v = 0.f;
    if (eg < EE){
      int node = eg<ego?eg:eg+1;
      v = (k<64) ? ws[F_NF + ((size_t)b*NN+node)*64 + k]
                 : ws[F_EF + ((size_t)b*EE+eg)*16 + (k-64)];
    }
    Fe[e][k] = v;
  }
  int tc = tid & 31, te = tid >> 5;     // te 0..15: 4 edges each; tc: 8 cols
  float acc[4][8];
  #pragma unroll
  for (int i=0;i<4;i++)
    #pragma unroll
    for (int j=0;j<8;j++) acc[i][j]=0.f;

  for (int c=0;c<5;c++){               // 5 chunks of K=16
    __syncthreads();                   // Bs reuse guard (also covers Fe staging on c=0)
    {                                  // stage Ws1 rows c*16..c*16+15 (contiguous 4096 floats)
      float4* dst = (float4*)&Bs[0][0];
      const float4* s4 = (const float4*)(Ws1 + (size_t)(c*16)*256);
      dst[tid]       = s4[tid];
      dst[tid + 512] = s4[tid + 512];
    }
    __syncthreads();
    #pragma unroll
    for (int kk=0; kk<16; kk+=4){
      float A[4][4];
      #pragma unroll
      for (int i=0;i<4;i++){
        float4 t4 = *(const float4*)&Fe[te*4+i][c*16+kk];   // broadcast per half-wave
        A[i][0]=t4.x; A[i][1]=t4.y; A[i][2]=t4.z; A[i][3]=t4.w;
      }
      #pragma unroll
      for (int q=0;q<4;q++){
        float4 b0 = *(const float4*)&Bs[kk+q][tc*8];
        float4 b1 = *(const float4*)&Bs[kk+q][tc*8+4];
        float bw[8] = {b0.x,b0.y,b0.z,b0.w,b1.x,b1.y,b1.z,b1.w};
        #pragma unroll
        for (int i=0;i<4;i++)
          #pragma unroll
          for (int j=0;j<8;j++) acc[i][j] = fmaf(A[i][q], bw[j], acc[i][j]);
      }
    }
  }
  float bs20 = bs2[0];
  #pragma unroll
  for (int i=0;i<4;i++){
    float p = 0.f;
    #pragma unroll
    for (int j=0;j<8;j++){
      float hcol = acc[i][j] + cv_s[tc*8+j];
      p += fmaxf(hcol,0.f)*w2_s[tc*8+j];
    }
    #pragma unroll
    for (int m=16;m>0;m>>=1) p += __shfl_xor(p, m, 64);   // reduce over tc (within half-wave)
    if (tc==0){
      int eg = tile*64 + te*4 + i;
      if (eg < EE) ws[F_SC2 + (size_t)b*EE + eg] = p + bs20;
    }
  }
}

// =============== top-5 (stable, ties -> lower index) + alpha softmax ===============
__global__ void k_topk(float* ws, float* out){
  int b = blockIdx.x, tid = threadIdx.x;
  __shared__ float sv[256]; __shared__ int si[256];
  __shared__ float tv[8];   __shared__ int tix[8];
  const float* s = ws + F_SC2 + (size_t)b*EE;
  float v0 = tid<EE ? s[tid] : -INFINITY;       int i0 = tid;
  float v1 = (tid+256)<EE ? s[tid+256] : -INFINITY; int i1 = tid+256;
  for (int t=0;t<5;t++){
    float bvv; int bii;
    if (v0 > v1 || (v0==v1 && i0<i1)){ bvv=v0; bii=i0; } else { bvv=v1; bii=i1; }
    sv[tid]=bvv; si[tid]=bii; __syncthreads();
    for (int st=128; st>0; st>>=1){
      if (tid<st){
        float ov=sv[tid+st]; int oi=si[tid+st];
        if (ov > sv[tid] || (ov==sv[tid] && oi<si[tid])){ sv[tid]=ov; si[tid]=oi; }
      }
      __syncthreads();
    }
    if (tid==0){ tv[t]=sv[0]; tix[t]=si[0]; }
    __syncthreads();
    int w = tix[t];
    if (i0==w) v0=-INFINITY;
    if (i1==w) v1=-INFINITY;
    __syncthreads();
  }
  if (tid==0){
    float m = tv[0];
    float ex[5]; float sum=0.f;
    for (int t=0;t<5;t++){ ex[t]=expf(tv[t]-m); sum+=ex[t]; }
    for (int t=0;t<5;t++){
      float al = ex[t]/sum;
      ws[F_ALPHA + (size_t)b*5+t] = al;
      ((int*)(ws + F_TKI))[b*5+t] = tix[t];
      out[O_TKI   + (size_t)b*5+t] = (float)tix[t];
      out[O_ALPHA + (size_t)b*5+t] = al;
    }
  }
}

// =============== selected hidden rows: hs[b,t,:] = relu(F_sel@Ws1[:80] + cvec) ===============
__global__ void k_hid(const int* ego_p, const float* Ws1, float* ws){
  int bt = blockIdx.x;               // b*5 + t
  int b = bt/5;
  int tid = threadIdx.x;
  __shared__ float fr[80];
  int e = ((const int*)(ws+F_TKI))[bt];
  int ego = *ego_p;
  int node = e<ego ? e : e+1;
  if (tid < 64)      fr[tid] = ws[F_NF + ((size_t)b*NN+node)*64 + tid];
  else if (tid < 80) fr[tid] = ws[F_EF + ((size_t)b*EE+e)*16 + (tid-64)];
  __syncthreads();
  float a = ws[F_CVEC + (size_t)b*256 + tid];
  for (int d=0;d<80;d++) a += fr[d]*Ws1[(size_t)d*256+tid];
  ws[F_HS + (size_t)bt*256 + tid] = fmaxf(a,0.f);
}

// =============== h_enc GEMM: out_sel[b,t,n] = (hs[b,t,:]·Ws2[:,1+n] + bs2[1+n])*alpha ===============
// grid (6, 128): r = 256-col chunk, g = pair of batches (10 rows). 1 col/thread, 10 acc.
// 768 blocks = 3/CU: TLP to hide L2 latency (round-4 k_enc at 192 blocks was latency-bound).
__global__ __launch_bounds__(256) void k_enc(const float* Ws2, const float* bs2,
                                             float* ws, float* out){
  int r = blockIdx.x, g = blockIdx.y, tid = threadIdx.x;
  int n = r*256 + tid;                 // 0..1535
  __shared__ float hs[10][256];
  __shared__ float al[10];
  int b0 = g*2;
  for (int l=tid; l<10*256; l+=256)
    hs[l>>8][l&255] = ws[F_HS + ((size_t)b0*5)*256 + l];
  if (tid<10) al[tid] = ws[F_ALPHA + (size_t)b0*5 + tid];
  __syncthreads();
  float acc[10];
  #pragma unroll
  for (int i=0;i<10;i++) acc[i]=0.f;
  const float* w2p = Ws2 + 1 + n;
  for (int j=0;j<256;j+=4){
    float w0 = w2p[(size_t)(j+0)*1537];
    float w1 = w2p[(size_t)(j+1)*1537];
    float w2 = w2p[(size_t)(j+2)*1537];
    float w3 = w2p[(size_t)(j+3)*1537];
    #pragma unroll
    for (int i=0;i<10;i++){
      float4 h = *(const float4*)&hs[i][j];
      acc[i] = fmaf(h.x,w0, fmaf(h.y,w1, fmaf(h.z,w2, fmaf(h.w,w3, acc[i]))));
    }
  }
  float bb = bs2[1+n];
  #pragma unroll
  for (int i=0;i<10;i++)
    out[O_SEL + ((size_t)(b0*5+i))*1536 + n] = (acc[i]+bb)*al[i];
}

extern "C" void kernel_launch(void* const* d_in, const int* in_sizes, int n_in,
                              void* d_out, int out_size, void* d_ws, size_t ws_size,
                              hipStream_t stream){
  const float* node_raw=(const float*)d_in[0];
  const float* edge_raw=(const float*)d_in[1];
  const int*  ego_p   =(const int*)d_in[2];
  const float* Wn =(const float*)d_in[3];  const float* bn =(const float*)d_in[4];
  const float* We =(const float*)d_in[5];  const float* be =(const float*)d_in[6];
  const float* Wq =(const float*)d_in[7];  const float* bq =(const float*)d_in[8];
  const float* Wkv=(const float*)d_in[9];  const float* bkv=(const float*)d_in[10];
  const float* Wiq=(const float*)d_in[11]; const float* biq=(const float*)d_in[12];
  const float* Wik=(const float*)d_in[13]; const float* bik=(const float*)d_in[14];
  const float* Wiv=(const float*)d_in[15]; const float* biv=(const float*)d_in[16];
  const float* Wo =(const float*)d_in[17]; const float* bo =(const float*)d_in[18];
  const float* Wf1=(const float*)d_in[19]; const float* bf1p=(const float*)d_in[20];
  const float* Wf2=(const float*)d_in[21]; const float* bf2p=(const float*)d_in[22];
  const float* Ws1=(const float*)d_in[23]; const float* bs1=(const float*)d_in[24];
  const float* Ws2=(const float*)d_in[25]; const float* bs2=(const float*)d_in[26];
  float* ws=(float*)d_ws;
  float* out=(float*)d_out;

  k_fuse<<<355,256,0,stream>>>(Wkv,bkv,Wik,bik,Wiv,biv,Wq,bq,Wiq,biq,ws);
  k_nf<<<(B*NN*64)/256,256,0,stream>>>(node_raw,Wn,bn,ws);
  k_ef<<<(B*EE*16)/256,256,0,stream>>>(edge_raw,We,be,ws);
  k_q<<<B,256,0,stream>>>(ego_p,ws);
  k_head<<<B*4,256,0,stream>>>(ego_p,ws);
  k_scores<<<B,256,0,stream>>>(ego_p,ws);
  k_softmax<<<B*4,256,0,stream>>>(ws);
  k_usum<<<B*4,128,0,stream>>>(ego_p,ws);
  k_bfinal<<<B,256,0,stream>>>(ego_p,Wo,bo,Wf1,bf1p,Wf2,bf2p,Ws1,bs1,ws,out);
  k_bigscore<<<dim3(8,B),512,0,stream>>>(ego_p,Ws1,Ws2,bs2,ws);
  k_topk<<<B,256,0,stream>>>(ws,out);
  k_hid<<<B*5,256,0,stream>>>(ego_p,Ws1,ws);
  k_enc<<<dim3(6,128),256,0,stream>>>(Ws2,bs2,ws,out);
}

// Round 9
// 245.712 us; speedup vs baseline: 1.6338x; 1.1710x over previous
//
#include <hip/hip_runtime.h>
#include <hip/hip_bf16.h>
#include <math.h>

constexpr int B = 256, NN = 512, EE = 511;

// ---- workspace layout (fp32 element offsets) ----
constexpr size_t F_NF    = 0;                               // node_feat  B*N*64
constexpr size_t F_EF    = F_NF   + (size_t)B*NN*64;        // edge_feat  B*E*16
constexpr size_t F_WCK   = F_EF   + (size_t)B*EE*16;        // fused K weight 144x256
constexpr size_t F_BCK   = F_WCK  + 144*256;
constexpr size_t F_WCV   = F_BCK  + 256;                    // fused V weight 144x256
constexpr size_t F_BCV   = F_WCV  + 144*256;
constexpr size_t F_WQ2   = F_BCV  + 256;                    // fused Q weight 64x256
constexpr size_t F_BQ2   = F_WQ2  + 64*256;
constexpr size_t F_Q     = F_BQ2  + 256;                    // (unused; kept for layout stability)
constexpr size_t F_AW    = F_Q    + (size_t)B*256;          // per (b,h) score weights 80
constexpr size_t F_C0    = F_AW   + (size_t)B*4*80;         // per (b,h) score const
constexpr size_t F_SC    = F_C0   + (size_t)B*4;            // scores B*4*E (dead after k_attn)
constexpr size_t F_US    = F_SC   + (size_t)B*4*EE;         // weighted sums B*4*80
constexpr size_t F_CEGO  = F_US   + (size_t)B*4*80;         // c_ego B*256
constexpr size_t F_CVEC  = F_CEGO + (size_t)B*256;          // cvec  B*256
constexpr size_t F_SC2   = F_CVEC + (size_t)B*256;          // edge scores B*E
constexpr size_t F_ALPHA = F_SC2  + (size_t)B*EE;           // B*5
constexpr size_t F_TKI   = F_ALPHA+ (size_t)B*5;            // B*5 (ints)
constexpr size_t F_HS    = F_SC;                            // selected hidden B*5*256 (aliases dead F_SC)

// ---- output layout (fp32 elements) ----
constexpr size_t O_HEGO  = 0;          // B*256
constexpr size_t O_SEL   = 65536;      // B*5*6*256
constexpr size_t O_TKI   = 2031616;    // B*5
constexpr size_t O_ALPHA = 2032896;    // B*5

// =============== weight fusion: Wck=WkvK@Wik, Wcv=WkvV@Wiv, Wq2=Wq@Wiq ===============
__global__ void k_fuse(const float* Wkv, const float* bkv, const float* Wik, const float* bik,
                       const float* Wiv, const float* biv, const float* Wq,  const float* bq,
                       const float* Wiq, const float* biq, float* ws){
  int t = blockIdx.x*256 + threadIdx.x;
  if (t < 36864){
    int r = t >> 8, c = t & 255;
    float a = 0.f;
    for (int m=0;m<256;m++) a += Wkv[(size_t)r*512+m] * Wik[(size_t)m*256+c];
    ws[F_WCK + t] = a;
  } else if (t < 37120){
    int c = t - 36864;
    float a = bik[c];
    for (int m=0;m<256;m++) a += bkv[m] * Wik[(size_t)m*256+c];
    ws[F_BCK + c] = a;
  } else if (t < 73984){
    int i = t - 37120; int r = i >> 8, c = i & 255;
    float a = 0.f;
    for (int m=0;m<256;m++) a += Wkv[(size_t)r*512+256+m] * Wiv[(size_t)m*256+c];
    ws[F_WCV + i] = a;
  } else if (t < 74240){
    int c = t - 73984;
    float a = biv[c];
    for (int m=0;m<256;m++) a += bkv[256+m] * Wiv[(size_t)m*256+c];
    ws[F_BCV + c] = a;
  } else if (t < 90624){
    int i = t - 74240; int r = i >> 8, c = i & 255;
    float a = 0.f;
    for (int m=0;m<256;m++) a += Wq[(size_t)r*256+m] * Wiq[(size_t)m*256+c];
    ws[F_WQ2 + i] = a;
  } else if (t < 90880){
    int c = t - 90624;
    float a = biq[c];
    for (int m=0;m<256;m++) a += bq[m] * Wiq[(size_t)m*256+c];
    ws[F_BQ2 + c] = a;
  }
}

// =============== node_feat = node_raw@Wn + bn ===============
__global__ void k_nf(const float* node_raw, const float* Wn, const float* bn, float* ws){
  size_t t = (size_t)blockIdx.x*256 + threadIdx.x;   // B*N*64 total
  int j = (int)(t & 63); size_t row = t >> 6;
  float a = bn[j];
  #pragma unroll
  for (int i=0;i<8;i++) a += node_raw[row*8+i] * Wn[(size_t)i*64+j];
  ws[F_NF + t] = a;
}

// =============== edge_feat = edge_raw@We + be ===============
__global__ void k_ef(const float* edge_raw, const float* We, const float* be, float* ws){
  size_t t = (size_t)blockIdx.x*256 + threadIdx.x;   // B*E*16 total
  int j = (int)(t & 15); size_t row = t >> 4;
  float a = be[j];
  #pragma unroll
  for (int i=0;i<3;i++) a += edge_raw[row*3+i] * We[(size_t)i*16+j];
  ws[F_EF + t] = a;
}

// =============== per (b,h): q (in-block), aw (80) and c0 so score = (c0 + F·aw)/8 ===============
__global__ void k_head(const int* ego_p, float* ws){
  int b = blockIdx.x >> 2, h = blockIdx.x & 3;
  int tid = threadIdx.x;
  __shared__ float qh[64];
  __shared__ float red[256];
  int ego = *ego_p;
  const float* egf = ws + F_NF + ((size_t)b*NN+ego)*64;
  if (tid < 64){                               // q[h*64+tid] = ego @ Wq2 col + bq2 (was k_q)
    int c = h*64 + tid;
    float a = ws[F_BQ2 + c];
    for (int i=0;i<64;i++) a += egf[i]*ws[F_WQ2 + (size_t)i*256 + c];
    qh[tid] = a;
  }
  __syncthreads();
  const float* Wck = ws + F_WCK;
  float p = 0.f;
  size_t awbase = F_AW + ((size_t)(b*4+h))*80;
  if (tid < 64){                               // neighbor-part weights (ei rows 80..143)
    const float* wr = Wck + (size_t)(80+tid)*256 + h*64;
    float a=0.f; for(int d=0;d<64;d++) a += wr[d]*qh[d];
    ws[awbase + tid] = a;
  } else if (tid < 80){                        // edge-part weights (rows 64..79)
    int i = tid-64;
    const float* wr = Wck + (size_t)(64+i)*256 + h*64;
    float a=0.f; for(int d=0;d<64;d++) a += wr[d]*qh[d];
    ws[awbase + 64 + i] = a;
  } else if (tid < 144){                       // ego-part constant (rows 0..63)
    int j = tid-80;
    const float* wr = Wck + (size_t)j*256 + h*64;
    float a=0.f; for(int d=0;d<64;d++) a += wr[d]*qh[d];
    p = egf[j] * a;
  } else if (tid < 208){                       // bias constant
    int d = tid-144;
    p = ws[F_BCK + h*64 + d] * qh[d];
  }
  red[tid]=p; __syncthreads();
  for (int s=128;s>0;s>>=1){ if(tid<s) red[tid]+=red[tid+s]; __syncthreads(); }
  if (tid==0) ws[F_C0 + b*4 + h] = red[0];
}

// =============== attention scores for all heads: grid (2,B), 1 edge/thread ===============
__global__ void k_scores(const int* ego_p, float* ws){
  int tile = blockIdx.x, b = blockIdx.y, tid = threadIdx.x;
  __shared__ float awz[4][80];
  __shared__ float c0s[4];
  for (int l=tid; l<320; l+=256) awz[l/80][l%80] = ws[F_AW + (size_t)b*320 + l];
  if (tid<4) c0s[tid] = ws[F_C0 + b*4 + tid];
  __syncthreads();
  int e = tile*256 + tid;
  if (e >= EE) return;
  int ego = *ego_p;
  int node = e < ego ? e : e+1;
  const float4* nr = (const float4*)(ws + F_NF + ((size_t)b*NN+node)*64);
  const float4* er = (const float4*)(ws + F_EF + ((size_t)b*EE+e)*16);
  float s[4] = {c0s[0],c0s[1],c0s[2],c0s[3]};
  #pragma unroll
  for (int i=0;i<16;i++){
    float4 x = nr[i];
    #pragma unroll
    for (int h=0;h<4;h++)
      s[h] += x.x*awz[h][i*4] + x.y*awz[h][i*4+1] + x.z*awz[h][i*4+2] + x.w*awz[h][i*4+3];
  }
  #pragma unroll
  for (int i=0;i<4;i++){
    float4 x = er[i];
    #pragma unroll
    for (int h=0;h<4;h++)
      s[h] += x.x*awz[h][64+i*4] + x.y*awz[h][64+i*4+1] + x.z*awz[h][64+i*4+2] + x.w*awz[h][64+i*4+3];
  }
  #pragma unroll
  for (int h=0;h<4;h++) ws[F_SC + ((size_t)(b*4+h))*EE + e] = s[h]*0.125f;
}

// =============== softmax + weighted sums fused, per (b,h) ===============
__global__ void k_attn(const int* ego_p, float* ws){
  int bh = blockIdx.x; int b = bh>>2; int tid = threadIdx.x;
  __shared__ float sc[512];
  __shared__ float red[256];
  const float* s = ws + F_SC + (size_t)bh*EE;
  float v0 = tid<EE ? s[tid] : -INFINITY;
  float v1 = (tid+256)<EE ? s[tid+256] : -INFINITY;
  red[tid] = fmaxf(v0,v1); __syncthreads();
  for (int st=128;st>0;st>>=1){ if(tid<st) red[tid]=fmaxf(red[tid],red[tid+st]); __syncthreads(); }
  float m = red[0]; __syncthreads();
  float e0 = tid<EE ? expf(v0-m) : 0.f;
  float e1 = (tid+256)<EE ? expf(v1-m) : 0.f;
  red[tid] = e0+e1; __syncthreads();
  for (int st=128;st>0;st>>=1){ if(tid<st) red[tid]+=red[tid+st]; __syncthreads(); }
  float inv = 1.f/red[0];
  sc[tid] = e0*inv;                // attn in LDS only (no global round-trip)
  sc[tid+256] = e1*inv;            // tid=255 -> sc[511]=0, never read
  __syncthreads();
  int ego = *ego_p;
  if (tid < 64){
    const float* base = ws + F_NF + (size_t)b*NN*64 + tid;
    float a = 0.f;
    for (int e=0;e<EE;e++){
      int node = e<ego?e:e+1;
      a += sc[e]*base[(size_t)node*64];
    }
    ws[F_US + (size_t)bh*80 + tid] = a;
  } else if (tid < 80){
    int d = tid-64;
    const float* base = ws + F_EF + (size_t)b*EE*16 + d;
    float a = 0.f;
    for (int e=0;e<EE;e++) a += sc[e]*base[(size_t)e*16];
    ws[F_US + (size_t)bh*80 + tid] = a;
  }
}

// =============== per-b tail: ctx -> c_ego -> h_ego_prime(out) + cvec ===============
__global__ void k_bfinal(const int* ego_p,
                         const float* Wo, const float* bo,
                         const float* Wf1, const float* bf1p,
                         const float* Wf2, const float* bf2p,
                         const float* Ws1, const float* bs1,
                         float* ws, float* out){
  int b = blockIdx.x, t = threadIdx.x;
  __shared__ float ego_s[64], us_s[4][80], ctx_s[256], cego_s[256], hf_s[256];
  int ego = *ego_p;
  if (t < 64) ego_s[t] = ws[F_NF + ((size_t)b*NN+ego)*64 + t];
  for (int l=t; l<320; l+=256) us_s[l/80][l%80] = ws[F_US + (size_t)b*320 + l];
  __syncthreads();
  {  // ctx = (sum attn * edge_input) @ Wcv + bcv
    int h = t >> 6;
    const float* Wcv = ws + F_WCV;
    float a = ws[F_BCV + t];
    for (int i=0;i<64;i++) a += ego_s[i]*Wcv[(size_t)i*256+t];
    for (int i=0;i<16;i++) a += us_s[h][64+i]*Wcv[(size_t)(64+i)*256+t];
    for (int i=0;i<64;i++) a += us_s[h][i]*Wcv[(size_t)(80+i)*256+t];
    ctx_s[t]=a;
  }
  __syncthreads();
  {  // c_ego = ctx @ Wo + bo
    float a = bo[t];
    for (int i=0;i<256;i++) a += ctx_s[i]*Wo[(size_t)i*256+t];
    cego_s[t]=a; ws[F_CEGO + (size_t)b*256+t]=a;
  }
  __syncthreads();
  {  // hf = relu([ego, c_ego] @ Wf1 + bf1)
    float a = bf1p[t];
    for (int i=0;i<64;i++)  a += ego_s[i]*Wf1[(size_t)i*256+t];
    for (int i=0;i<256;i++) a += cego_s[i]*Wf1[(size_t)(64+i)*256+t];
    hf_s[t]=fmaxf(a,0.f);
  }
  __syncthreads();
  {  // h_ego_prime = hf @ Wf2 + bf2
    float a = bf2p[t];
    for (int i=0;i<256;i++) a += hf_s[i]*Wf2[(size_t)i*256+t];
    out[O_HEGO + (size_t)b*256+t] = a;
  }
  {  // cvec = c_ego @ Ws1[80:336] + bs1
    float a = bs1[t];
    for (int i=0;i<256;i++) a += cego_s[i]*Ws1[(size_t)(80+i)*256+t];
    ws[F_CVEC + (size_t)b*256+t]=a;
  }
}

// =============== edge score GEMM: score[b,e] = relu(F@Ws1[:80]+cvec)·w2col0 + bs2[0] ===============
// v4: B-reads conflict-free — lane tc reads ADJACENT float4s at cols {tc*4} and {128+tc*4}
// (16B lane stride; the round-8 tc*8 mapping had 32B stride = 4-8 way conflict, 11.1M counts).
__global__ __launch_bounds__(512) void k_bigscore(const int* ego_p, const float* Ws1,
                                                  const float* Ws2, const float* bs2, float* ws){
  int tile = blockIdx.x, b = blockIdx.y;
  int tid = threadIdx.x;
  __shared__ float Fe[64][80];          // 20 KB, [edge][k]
  __shared__ float Bs[16][256];         // 16 KB, k-chunk of Ws1
  __shared__ float cv_s[256], w2_s[256];
  int ego = *ego_p;
  if (tid < 256){
    cv_s[tid] = ws[F_CVEC + (size_t)b*256 + tid];
    w2_s[tid] = Ws2[(size_t)tid*1537];          // Ws2[:,0]
  }
  for (int l=tid; l<80*64; l+=512){
    int e = l/80, k = l - e*80;        // consecutive lanes -> consecutive k: coalesced + conflict-free
    int eg = tile*64 + e;
    float v = 0.f;
    if (eg < EE){
      int node = eg<ego?eg:eg+1;
      v = (k<64) ? ws[F_NF + ((size_t)b*NN+node)*64 + k]
                 : ws[F_EF + ((size_t)b*EE+eg)*16 + (k-64)];
    }
    Fe[e][k] = v;
  }
  int tc = tid & 31, te = tid >> 5;     // te 0..15: 4 edges each; tc: cols {tc*4..+3, 128+tc*4..+3}
  float acc[4][8];
  #pragma unroll
  for (int i=0;i<4;i++)
    #pragma unroll
    for (int j=0;j<8;j++) acc[i][j]=0.f;

  for (int c=0;c<5;c++){               // 5 chunks of K=16
    __syncthreads();                   // Bs reuse guard (also covers Fe staging on c=0)
    {                                  // stage Ws1 rows c*16..c*16+15 (contiguous 4096 floats)
      float4* dst = (float4*)&Bs[0][0];
      const float4* s4 = (const float4*)(Ws1 + (size_t)(c*16)*256);
      dst[tid]       = s4[tid];
      dst[tid + 512] = s4[tid + 512];
    }
    __syncthreads();
    #pragma unroll
    for (int kk=0; kk<16; kk+=4){
      float A[4][4];
      #pragma unroll
      for (int i=0;i<4;i++){
        float4 t4 = *(const float4*)&Fe[te*4+i][c*16+kk];   // broadcast per half-wave
        A[i][0]=t4.x; A[i][1]=t4.y; A[i][2]=t4.z; A[i][3]=t4.w;
      }
      #pragma unroll
      for (int q=0;q<4;q++){
        float4 b0 = *(const float4*)&Bs[kk+q][tc*4];        // 16B lane stride: conflict-free
        float4 b1 = *(const float4*)&Bs[kk+q][128 + tc*4];
        float bw[8] = {b0.x,b0.y,b0.z,b0.w,b1.x,b1.y,b1.z,b1.w};
        #pragma unroll
        for (int i=0;i<4;i++)
          #pragma unroll
          for (int j=0;j<8;j++) acc[i][j] = fmaf(A[i][q], bw[j], acc[i][j]);
      }
    }
  }
  float bs20 = bs2[0];
  #pragma unroll
  for (int i=0;i<4;i++){
    float p = 0.f;
    #pragma unroll
    for (int j=0;j<4;j++){
      int col = tc*4 + j;
      float hcol = acc[i][j] + cv_s[col];
      p += fmaxf(hcol,0.f)*w2_s[col];
    }
    #pragma unroll
    for (int j=0;j<4;j++){
      int col = 128 + tc*4 + j;
      float hcol = acc[i][4+j] + cv_s[col];
      p += fmaxf(hcol,0.f)*w2_s[col];
    }
    #pragma unroll
    for (int m=16;m>0;m>>=1) p += __shfl_xor(p, m, 64);   // reduce over tc (within half-wave)
    if (tc==0){
      int eg = tile*64 + te*4 + i;
      if (eg < EE) ws[F_SC2 + (size_t)b*EE + eg] = p + bs20;
    }
  }
}

// =============== top-5 (stable, ties -> lower index) + alpha softmax ===============
__global__ void k_topk(float* ws, float* out){
  int b = blockIdx.x, tid = threadIdx.x;
  __shared__ float sv[256]; __shared__ int si[256];
  __shared__ float tv[8];   __shared__ int tix[8];
  const float* s = ws + F_SC2 + (size_t)b*EE;
  float v0 = tid<EE ? s[tid] : -INFINITY;       int i0 = tid;
  float v1 = (tid+256)<EE ? s[tid+256] : -INFINITY; int i1 = tid+256;
  for (int t=0;t<5;t++){
    float bvv; int bii;
    if (v0 > v1 || (v0==v1 && i0<i1)){ bvv=v0; bii=i0; } else { bvv=v1; bii=i1; }
    sv[tid]=bvv; si[tid]=bii; __syncthreads();
    for (int st=128; st>0; st>>=1){
      if (tid<st){
        float ov=sv[tid+st]; int oi=si[tid+st];
        if (ov > sv[tid] || (ov==sv[tid] && oi<si[tid])){ sv[tid]=ov; si[tid]=oi; }
      }
      __syncthreads();
    }
    if (tid==0){ tv[t]=sv[0]; tix[t]=si[0]; }
    __syncthreads();
    int w = tix[t];
    if (i0==w) v0=-INFINITY;
    if (i1==w) v1=-INFINITY;
    __syncthreads();
  }
  if (tid==0){
    float m = tv[0];
    float ex[5]; float sum=0.f;
    for (int t=0;t<5;t++){ ex[t]=expf(tv[t]-m); sum+=ex[t]; }
    for (int t=0;t<5;t++){
      float al = ex[t]/sum;
      ws[F_ALPHA + (size_t)b*5+t] = al;
      ((int*)(ws + F_TKI))[b*5+t] = tix[t];
      out[O_TKI   + (size_t)b*5+t] = (float)tix[t];
      out[O_ALPHA + (size_t)b*5+t] = al;
    }
  }
}

// =============== selected hidden rows: hs[b,t,:] = relu(F_sel@Ws1[:80] + cvec) ===============
__global__ void k_hid(const int* ego_p, const float* Ws1, float* ws){
  int bt = blockIdx.x;               // b*5 + t
  int b = bt/5;
  int tid = threadIdx.x;
  __shared__ float fr[80];
  int e = ((const int*)(ws+F_TKI))[bt];
  int ego = *ego_p;
  int node = e<ego ? e : e+1;
  if (tid < 64)      fr[tid] = ws[F_NF + ((size_t)b*NN+node)*64 + tid];
  else if (tid < 80) fr[tid] = ws[F_EF + ((size_t)b*EE+e)*16 + (tid-64)];
  __syncthreads();
  float a = ws[F_CVEC + (size_t)b*256 + tid];
  for (int d=0;d<80;d++) a += fr[d]*Ws1[(size_t)d*256+tid];
  ws[F_HS + (size_t)bt*256 + tid] = fmaxf(a,0.f);
}

// =============== h_enc GEMM: out_sel[b,t,n] = (hs[b,t,:]·Ws2[:,1+n] + bs2[1+n])*alpha ===============
__global__ __launch_bounds__(256) void k_enc(const float* Ws2, const float* bs2,
                                             float* ws, float* out){
  int r = blockIdx.x, g = blockIdx.y, tid = threadIdx.x;
  int n = r*256 + tid;                 // 0..1535
  __shared__ float hs[10][256];
  __shared__ float al[10];
  int b0 = g*2;
  for (int l=tid; l<10*256; l+=256)
    hs[l>>8][l&255] = ws[F_HS + ((size_t)b0*5)*256 + l];
  if (tid<10) al[tid] = ws[F_ALPHA + (size_t)b0*5 + tid];
  __syncthreads();
  float acc[10];
  #pragma unroll
  for (int i=0;i<10;i++) acc[i]=0.f;
  const float* w2p = Ws2 + 1 + n;
  for (int j=0;j<256;j+=4){
    float w0 = w2p[(size_t)(j+0)*1537];
    float w1 = w2p[(size_t)(j+1)*1537];
    float w2 = w2p[(size_t)(j+2)*1537];
    float w3 = w2p[(size_t)(j+3)*1537];
    #pragma unroll
    for (int i=0;i<10;i++){
      float4 h = *(const float4*)&hs[i][j];
      acc[i] = fmaf(h.x,w0, fmaf(h.y,w1, fmaf(h.z,w2, fmaf(h.w,w3, acc[i]))));
    }
  }
  float bb = bs2[1+n];
  #pragma unroll
  for (int i=0;i<10;i++)
    out[O_SEL + ((size_t)(b0*5+i))*1536 + n] = (acc[i]+bb)*al[i];
}

extern "C" void kernel_launch(void* const* d_in, const int* in_sizes, int n_in,
                              void* d_out, int out_size, void* d_ws, size_t ws_size,
                              hipStream_t stream){
  const float* node_raw=(const float*)d_in[0];
  const float* edge_raw=(const float*)d_in[1];
  const int*  ego_p   =(const int*)d_in[2];
  const float* Wn =(const float*)d_in[3];  const float* bn =(const float*)d_in[4];
  const float* We =(const float*)d_in[5];  const float* be =(const float*)d_in[6];
  const float* Wq =(const float*)d_in[7];  const float* bq =(const float*)d_in[8];
  const float* Wkv=(const float*)d_in[9];  const float* bkv=(const float*)d_in[10];
  const float* Wiq=(const float*)d_in[11]; const float* biq=(const float*)d_in[12];
  const float* Wik=(const float*)d_in[13]; const float* bik=(const float*)d_in[14];
  const float* Wiv=(const float*)d_in[15]; const float* biv=(const float*)d_in[16];
  const float* Wo =(const float*)d_in[17]; const float* bo =(const float*)d_in[18];
  const float* Wf1=(const float*)d_in[19]; const float* bf1p=(const float*)d_in[20];
  const float* Wf2=(const float*)d_in[21]; const float* bf2p=(const float*)d_in[22];
  const float* Ws1=(const float*)d_in[23]; const float* bs1=(const float*)d_in[24];
  const float* Ws2=(const float*)d_in[25]; const float* bs2=(const float*)d_in[26];
  float* ws=(float*)d_ws;
  float* out=(float*)d_out;

  k_fuse<<<355,256,0,stream>>>(Wkv,bkv,Wik,bik,Wiv,biv,Wq,bq,Wiq,biq,ws);
  k_nf<<<(B*NN*64)/256,256,0,stream>>>(node_raw,Wn,bn,ws);
  k_ef<<<(B*EE*16)/256,256,0,stream>>>(edge_raw,We,be,ws);
  k_head<<<B*4,256,0,stream>>>(ego_p,ws);
  k_scores<<<dim3(2,B),256,0,stream>>>(ego_p,ws);
  k_attn<<<B*4,256,0,stream>>>(ego_p,ws);
  k_bfinal<<<B,256,0,stream>>>(ego_p,Wo,bo,Wf1,bf1p,Wf2,bf2p,Ws1,bs1,ws,out);
  k_bigscore<<<dim3(8,B),512,0,stream>>>(ego_p,Ws1,Ws2,bs2,ws);
  k_topk<<<B,256,0,stream>>>(ws,out);
  k_hid<<<B*5,256,0,stream>>>(ego_p,Ws1,ws);
  k_enc<<<dim3(6,128),256,0,stream>>>(Ws2,bs2,ws,out);
}